// Round 6
// baseline (3440.827 us; speedup 1.0000x reference)
//
#include <hip/hip_runtime.h>

// ---------------------------------------------------------------------------
// Problem constants
// ---------------------------------------------------------------------------
#define NB    128
#define HD    100
#define NU    20000
#define NTG   10000
#define NTREE 30000
#define NG    30000
#define TT    20
#define EG    200000
#define ET    60000
#define VOC   50000

#define ESTR  352   // Etab row stride (u16): 3 segments of 112
#define GSTR  352   // gate LDS row stride

typedef unsigned short u16;
typedef unsigned int   u32;
typedef __attribute__((ext_vector_type(8))) short short8;
typedef __attribute__((ext_vector_type(4))) float floatx4;

__device__ __forceinline__ float sigmoidf_(float x) {
    return __fdividef(1.f, 1.f + __expf(-x));
}
__device__ __forceinline__ float tanhf_(float x) {
    return 1.f - __fdividef(2.f, __expf(2.f * x) + 1.f);
}
__device__ __forceinline__ u16 f2bf(float f) {
    u32 u = __float_as_uint(f);
    u32 r = (u + 0x7fffu + ((u >> 16) & 1u)) >> 16;
    return (u16)r;
}
__device__ __forceinline__ float bf2f(u16 h) {
    return __uint_as_float(((u32)h) << 16);
}

// ---------------------------------------------------------------------------
// Wave-autonomous fused 2-layer GRU: 1 wave (64 thr) owns 16 rows for all TT
// steps. h state in registers (MFMA B-frag layout + fp32 carry); weights
// streamed from global (L2-hot); gates transpose through wave-private LDS.
// Biases folded into the K=100 slot (h col100 == 1, W col100 == bias).
// Etab layout [VOC][3*112] (stride 352), includes bih0.
// ---------------------------------------------------------------------------
struct GruProb {
    const u16*   Etab;     // [VOC][352]
    const int*   nodes;    // [M][TT]
    const float* h0;       // [2][M][100] fp32
    const u16*   Whh0;     // [320][128] (col100 = bhh0)
    const u16*   Wih1;     // (col100 = bih1)
    const u16*   Whh1;     // (col100 = bhh1)
    u16*         hout;     // [M][128]
    int          M;
};

__global__ __launch_bounds__(64) void gru_fused3(GruProb Pg, GruProb Pt, int gwaves)
{
    const bool isg = (int)blockIdx.x < gwaves;
    const GruProb P = isg ? Pg : Pt;
    const int w  = isg ? blockIdx.x : blockIdx.x - gwaves;
    const int M  = P.M;

    __shared__ u16 g1[16 * GSTR];   // gate buffer (3 segments of 112)
    __shared__ u16 g2[16 * 128];    // hn buffer (layer 1)

    const int lane = threadIdx.x;
    const int fr   = lane & 15, quad = lane >> 4;
    const int row  = w * 16 + fr;   // M is a multiple of 16

    // h state: bf16 B-frags + fp32 carry
    short8 h0A[4], h1A[4];
    float  h0f[4][8], h1f[4][8];
#pragma unroll
    for (int kk = 0; kk < 4; ++kk) {
#pragma unroll
        for (int j = 0; j < 8; ++j) {
            int c = 32 * kk + 8 * quad + j;
            float v0 = 0.f, v1 = 0.f;
            u16 b0 = 0, b1 = 0;
            if (c < 100) {
                v0 = P.h0[(size_t)row * 100 + c];
                v1 = P.h0[(size_t)(M + row) * 100 + c];
                b0 = f2bf(v0); b1 = f2bf(v1);
            } else if (c == 100) {
                b0 = 0x3F80; b1 = 0x3F80;   // constant 1.0 (bias slot)
            }
            h0f[kk][j] = v0; h1f[kk][j] = v1;
            h0A[kk][j] = (short)b0; h1A[kk][j] = (short)b1;
        }
    }

    // preload Etab x-gates for t=0
    short8 xp0[4], xp1[4], xp2[4];
    {
        int nd = P.nodes[(size_t)row * TT];
        const u16* ex = P.Etab + (size_t)nd * ESTR + 8 * quad;
#pragma unroll
        for (int kk = 0; kk < 4; ++kk) {
            xp0[kk] = *(const short8*)(ex + 32 * kk);
            xp1[kk] = *(const short8*)(ex + 112 + 32 * kk);
            xp2[kk] = *(const short8*)(ex + 224 + 32 * kk);
        }
    }

    for (int t = 0; t < TT; ++t) {
        // prefetch next node id (consumed after combine0)
        int nd_next = (t + 1 < TT) ? P.nodes[(size_t)row * TT + t + 1] : 0;

        // ---- GEMM0: Gh0^T = Whh0 . h0^T -> g1 ----
        for (int s = 0; s < 19; ++s) {
            const u16* wp = P.Whh0 + (size_t)(16 * s + fr) * 128 + 8 * quad;
            floatx4 acc = {0.f, 0.f, 0.f, 0.f};
#pragma unroll
            for (int kk = 0; kk < 4; ++kk)
                acc = __builtin_amdgcn_mfma_f32_16x16x32_bf16(
                    *(const short8*)(wp + 32 * kk), h0A[kk], acc, 0, 0, 0);
            int g0 = 16 * s + quad * 4;            // gate col base (mult of 4)
            int seg = g0 / 100;
            int pos = seg * 112 + (g0 - seg * 100);
            u32 lo = (u32)f2bf(acc[0]) | ((u32)f2bf(acc[1]) << 16);
            u32 hi = (u32)f2bf(acc[2]) | ((u32)f2bf(acc[3]) << 16);
            *(uint2*)&g1[fr * GSTR + pos] = make_uint2(lo, hi);
        }
        __syncthreads();

        // ---- combine layer 0 (x-gates from xp regs; updates h0A/h0f) ----
#pragma unroll
        for (int kk = 0; kk < 4; ++kk) {
            int off = 32 * kk + 8 * quad;
            short8 hr8 = *(const short8*)&g1[fr * GSTR + off];
            short8 hz8 = *(const short8*)&g1[fr * GSTR + 112 + off];
            short8 hn8 = *(const short8*)&g1[fr * GSTR + 224 + off];
#pragma unroll
            for (int j = 0; j < 8; ++j) {
                int c = off + j;
                if (c >= 100) continue;
                float r  = sigmoidf_(bf2f((u16)xp0[kk][j]) + bf2f((u16)hr8[j]));
                float zz = sigmoidf_(bf2f((u16)xp1[kk][j]) + bf2f((u16)hz8[j]));
                float ng = tanhf_(bf2f((u16)xp2[kk][j]) + r * bf2f((u16)hn8[j]));
                float o  = (1.f - zz) * ng + zz * h0f[kk][j];
                h0f[kk][j] = o;
                h0A[kk][j] = (short)f2bf(o);
            }
        }

        // ---- prefetch Etab for t+1 (covered by GEMM1) ----
        if (t + 1 < TT) {
            const u16* ex = P.Etab + (size_t)nd_next * ESTR + 8 * quad;
#pragma unroll
            for (int kk = 0; kk < 4; ++kk) {
                xp0[kk] = *(const short8*)(ex + 32 * kk);
                xp1[kk] = *(const short8*)(ex + 112 + 32 * kk);
                xp2[kk] = *(const short8*)(ex + 224 + 32 * kk);
            }
        }

        // ---- GEMM1: Gx1^T = Wih1.h0^T, Gh1^T = Whh1.h1^T ----
        // r,z: store sum; n: xn -> g1 seg2, hn -> g2
        for (int s = 0; s < 19; ++s) {
            const u16* wpx = P.Wih1 + (size_t)(16 * s + fr) * 128 + 8 * quad;
            const u16* wph = P.Whh1 + (size_t)(16 * s + fr) * 128 + 8 * quad;
            floatx4 ax = {0.f, 0.f, 0.f, 0.f};
            floatx4 ah = {0.f, 0.f, 0.f, 0.f};
#pragma unroll
            for (int kk = 0; kk < 4; ++kk) {
                ax = __builtin_amdgcn_mfma_f32_16x16x32_bf16(
                    *(const short8*)(wpx + 32 * kk), h0A[kk], ax, 0, 0, 0);
                ah = __builtin_amdgcn_mfma_f32_16x16x32_bf16(
                    *(const short8*)(wph + 32 * kk), h1A[kk], ah, 0, 0, 0);
            }
            int g0 = 16 * s + quad * 4;
            if (g0 < 200) {
                int seg = g0 / 100;
                int pos = seg * 112 + (g0 - seg * 100);
                u32 lo = (u32)f2bf(ax[0] + ah[0]) | ((u32)f2bf(ax[1] + ah[1]) << 16);
                u32 hi = (u32)f2bf(ax[2] + ah[2]) | ((u32)f2bf(ax[3] + ah[3]) << 16);
                *(uint2*)&g1[fr * GSTR + pos] = make_uint2(lo, hi);
            } else {
                int pos = 224 + (g0 - 200) + (g0 >= 300 ? 12 : 0);  // g0==300 -> 336 (garbage)
                u32 lo = (u32)f2bf(ax[0]) | ((u32)f2bf(ax[1]) << 16);
                u32 hi = (u32)f2bf(ax[2]) | ((u32)f2bf(ax[3]) << 16);
                *(uint2*)&g1[fr * GSTR + pos] = make_uint2(lo, hi);
                u32 lo2 = (u32)f2bf(ah[0]) | ((u32)f2bf(ah[1]) << 16);
                u32 hi2 = (u32)f2bf(ah[2]) | ((u32)f2bf(ah[3]) << 16);
                *(uint2*)&g2[fr * 128 + (g0 - 200)] = make_uint2(lo2, hi2);
            }
        }
        __syncthreads();

        // ---- combine layer 1 ----
#pragma unroll
        for (int kk = 0; kk < 4; ++kk) {
            int off = 32 * kk + 8 * quad;
            short8 sr8 = *(const short8*)&g1[fr * GSTR + off];
            short8 sz8 = *(const short8*)&g1[fr * GSTR + 112 + off];
            short8 xn8 = *(const short8*)&g1[fr * GSTR + 224 + off];
            short8 hn8 = *(const short8*)&g2[fr * 128 + off];
#pragma unroll
            for (int j = 0; j < 8; ++j) {
                int c = off + j;
                if (c >= 100) continue;
                float r  = sigmoidf_(bf2f((u16)sr8[j]));
                float zz = sigmoidf_(bf2f((u16)sz8[j]));
                float ng = tanhf_(bf2f((u16)xn8[j]) + r * bf2f((u16)hn8[j]));
                float o  = (1.f - zz) * ng + zz * h1f[kk][j];
                h1f[kk][j] = o;
                h1A[kk][j] = (short)f2bf(o);
            }
        }
        // WAR on g1/g2 vs next GEMM0 is safe: DS ops from one wave are in-order.
    }

    // ---- write final top-layer hidden, bf16 [M][128] (col100==1 harmless) ----
#pragma unroll
    for (int kk = 0; kk < 4; ++kk)
        *(short8*)(P.hout + (size_t)row * 128 + 32 * kk + 8 * quad) = h1A[kk];
}

// ---------------------------------------------------------------------------
// bf16 MFMA GEMM (Etab build + GAT feature GEMMs). ldcseg!=0 -> segmented
// column mapping col -> (col/100)*112 + col%100, cols >=300 dropped.
// ---------------------------------------------------------------------------
#define LDST 40
__global__ __launch_bounds__(256) void gemm_mfma(
    const u16* __restrict__ A, const u16* __restrict__ B,
    float* __restrict__ Cf, u16* __restrict__ Cb,
    int M, int N, int Kt, int lda, int ldw, int ldc, int ldcseg)
{
    const int m0 = blockIdx.x * 64;
    if (m0 >= M) return;
    const int n0 = blockIdx.y * 64;

    __shared__ u16 Als[64 * LDST];
    __shared__ u16 Wls[64 * LDST];

    const int tid  = threadIdx.x;
    const int wave = tid >> 6, lane = tid & 63;
    const int row  = tid >> 2, part = (tid & 3) * 8;
    const int fr   = lane & 15, quad = lane >> 4;

    floatx4 acc[4];
#pragma unroll
    for (int t = 0; t < 4; ++t) acc[t] = (floatx4){0.f, 0.f, 0.f, 0.f};

    const int am = m0 + row;  const bool aok = am < M;
    const int wn = n0 + row;  const bool wok = wn < N;
    const uint4 z4 = {0u, 0u, 0u, 0u};

    for (int kk = 0; kk < Kt; ++kk) {
        uint4 av = aok ? *(const uint4*)(A + (size_t)am * lda + kk * 32 + part) : z4;
        uint4 wv = wok ? *(const uint4*)(B + (size_t)wn * ldw + kk * 32 + part) : z4;
        __syncthreads();
        *(uint4*)&Als[row * LDST + part] = av;
        *(uint4*)&Wls[row * LDST + part] = wv;
        __syncthreads();
        short8 af = *(const short8*)&Als[((wave << 4) + fr) * LDST + quad * 8];
#pragma unroll
        for (int t = 0; t < 4; ++t) {
            short8 bf = *(const short8*)&Wls[((t << 4) + fr) * LDST + quad * 8];
            acc[t] = __builtin_amdgcn_mfma_f32_16x16x32_bf16(af, bf, acc[t], 0, 0, 0);
        }
    }

    const int orow0 = m0 + (wave << 4) + quad * 4;
#pragma unroll
    for (int t = 0; t < 4; ++t) {
        int col = n0 + (t << 4) + fr;
        if (col >= N) continue;
#pragma unroll
        for (int r = 0; r < 4; ++r) {
            int mr = orow0 + r;
            if (mr >= M) continue;
            float v = acc[t][r];
            if (ldcseg) {
                if (col < 300) {
                    int seg = col / 100;
                    Cb[(size_t)mr * ldc + seg * 112 + (col - seg * 100)] = f2bf(v);
                }
            } else {
                if (Cf) Cf[(size_t)mr * ldc + col] = v;
                if (Cb) Cb[(size_t)mr * ldc + col] = f2bf(v);
            }
        }
    }
}

// ---------------------------------------------------------------------------
// fp32 tiled GEMM (user-embed MLP only)
// ---------------------------------------------------------------------------
__global__ __launch_bounds__(256) void gemm_nt(
    const float* __restrict__ A, const float* __restrict__ W,
    const float* __restrict__ bias, float* __restrict__ C,
    int M, int N, int K, int relu)
{
    const int m0 = blockIdx.x * 64;
    const int n0 = blockIdx.y * 64;
    __shared__ float As[20][68];
    __shared__ float Ws[20][68];
    const int tid = threadIdx.x;
    const int r0 = (tid >> 4) * 4;
    const int c0 = (tid & 15) * 4;
    int sr[5], sk[5];
#pragma unroll
    for (int it = 0; it < 5; ++it) {
        int idx = tid + it * 256;
        sr[it] = idx / 20; sk[it] = idx - sr[it] * 20;
    }
    float acc[4][4];
#pragma unroll
    for (int i = 0; i < 4; ++i)
#pragma unroll
        for (int j = 0; j < 4; ++j) acc[i][j] = 0.f;
    const int nch = (K + 19) / 20;
    for (int ch = 0; ch < nch; ++ch) {
        const int k0 = ch * 20;
#pragma unroll
        for (int it = 0; it < 5; ++it) {
            int m = m0 + sr[it], k = k0 + sk[it];
            float va = 0.f, vw = 0.f;
            if (k < K) {
                if (m < M) va = A[(size_t)m * K + k];
                int n = n0 + sr[it];
                if (n < N) vw = W[(size_t)n * K + k];
            }
            As[sk[it]][sr[it]] = va;
            Ws[sk[it]][sr[it]] = vw;
        }
        __syncthreads();
#pragma unroll
        for (int kkk = 0; kkk < 20; ++kkk) {
            float4 a = *(const float4*)&As[kkk][r0];
            float4 w = *(const float4*)&Ws[kkk][c0];
            float av[4] = {a.x, a.y, a.z, a.w};
            float wv[4] = {w.x, w.y, w.z, w.w};
#pragma unroll
            for (int i = 0; i < 4; ++i)
#pragma unroll
                for (int j = 0; j < 4; ++j)
                    acc[i][j] = fmaf(av[i], wv[j], acc[i][j]);
        }
        __syncthreads();
    }
#pragma unroll
    for (int i = 0; i < 4; ++i) {
        int m = m0 + r0 + i;
        if (m >= M) continue;
#pragma unroll
        for (int j = 0; j < 4; ++j) {
            int n = n0 + c0 + j;
            if (n >= N) continue;
            float v = acc[i][j] + (bias ? bias[n] : 0.f);
            if (relu) v = fmaxf(v, 0.f);
            C[(size_t)m * N + n] = v;
        }
    }
}

// fp32 [M][K] -> bf16 [Mp][ldk]; col K..ldk zero, except col 100 gets
// app[n] (if app) or 1.0 (if appone) — the K-slot bias fold.
__global__ void convert_pad2(const float* __restrict__ src, u16* __restrict__ dst,
                             int M, int Mp, int K, int ldk,
                             const float* __restrict__ app, int appone)
{
    int t = blockIdx.x * blockDim.x + threadIdx.x;
    if (t >= Mp * ldk) return;
    int n = t / ldk, c = t - n * ldk;
    u16 o = 0;
    if (n < M) {
        if (c < K) o = f2bf(src[(size_t)n * K + c]);
        else if (c == 100) {
            if (app) o = f2bf(app[n]);
            else if (appone) o = 0x3F80;
        }
    }
    dst[t] = o;
}

// xg (bf16 [NG][128]) = concat(hg[:128], ue, hg[128:])
__global__ void build_xg_bf(const u16* __restrict__ hgb, const float* __restrict__ ue,
                            u16* __restrict__ xgb)
{
    int t = blockIdx.x * blockDim.x + threadIdx.x;
    if (t >= NG * 128) return;
    int n = t >> 7, c = t & 127;
    u16 o = 0;
    if (n < NB)           o = hgb[n * 128 + c];
    else if (n < NB + NU) { if (c < HD) o = f2bf(ue[(size_t)(n - NB) * HD + c]); }
    else                  o = hgb[(size_t)(n - NU) * 128 + c];
    xgb[t] = o;
}

// tree roots: hb rows[0:128) <- xg_final fp32
__global__ void set_roots(const float* __restrict__ src, u16* __restrict__ hb)
{
    int t = blockIdx.x * blockDim.x + threadIdx.x;
    if (t >= NB * HD) return;
    int n = t / HD, c = t - n * HD;
    hb[(size_t)n * 128 + c] = f2bf(src[t]);
}

// ---------------------------------------------------------------------------
// CSR build
// ---------------------------------------------------------------------------
__global__ void csr_count(const int* __restrict__ ei, int E, int N, int* __restrict__ cnt)
{
    int e = blockIdx.x * blockDim.x + threadIdx.x;
    if (e >= E + N) return;
    int dst = (e < E) ? ei[E + e] : e - E;
    atomicAdd(&cnt[dst], 1);
}

__global__ void csr_scan(const int* __restrict__ cnt, int* __restrict__ off,
                         int* __restrict__ cur, int N)
{
    __shared__ int part[256];
    const int tid = threadIdx.x;
    const int per = (N + 255) / 256;
    const int i0 = tid * per;
    const int i1 = min(i0 + per, N);
    int s = 0;
    for (int i = i0; i < i1; ++i) s += cnt[i];
    part[tid] = s;
    __syncthreads();
    for (int o = 1; o < 256; o <<= 1) {
        int u = (tid >= o) ? part[tid - o] : 0;
        __syncthreads();
        part[tid] += u;
        __syncthreads();
    }
    int base = part[tid] - s;
    for (int i = i0; i < i1; ++i) {
        off[i] = base; cur[i] = base;
        base += cnt[i];
    }
    if (tid == 255) off[N] = part[255];
}

__global__ void csr_scatter(const int* __restrict__ ei, int E, int N,
                            int* __restrict__ cur, int* __restrict__ eidx)
{
    int e = blockIdx.x * blockDim.x + threadIdx.x;
    if (e >= E + N) return;
    int dst = (e < E) ? ei[E + e] : e - E;
    int pos = atomicAdd(&cur[dst], 1);
    eidx[pos] = e;
}

// ---------------------------------------------------------------------------
// GAT pieces (feat is bf16)
// ---------------------------------------------------------------------------
__global__ void gat_es_ed(const u16* __restrict__ feat, const float* __restrict__ asrc,
                          const float* __restrict__ adst, float* __restrict__ es,
                          float* __restrict__ ed, int N, int heads, int C)
{
    int gid = blockIdx.x * blockDim.x + threadIdx.x;
    if (gid >= N * heads) return;
    int n = gid / heads, hd = gid - n * heads;
    const u16* hp = feat + ((size_t)n * heads + hd) * C;
    const float* as = asrc + (size_t)hd * C;
    const float* ad = adst + (size_t)hd * C;
    float s1 = 0.f, s2 = 0.f;
    for (int c = 0; c < C; c += 4) {
        uint2 pk = *(const uint2*)(hp + c);
        float v0 = bf2f((u16)(pk.x & 0xffff)), v1 = bf2f((u16)(pk.x >> 16));
        float v2 = bf2f((u16)(pk.y & 0xffff)), v3 = bf2f((u16)(pk.y >> 16));
        s1 += v0 * as[c] + v1 * as[c + 1] + v2 * as[c + 2] + v3 * as[c + 3];
        s2 += v0 * ad[c] + v1 * ad[c + 1] + v2 * ad[c + 2] + v3 * ad[c + 3];
    }
    es[gid] = s1; ed[gid] = s2;
}

__device__ __forceinline__ void atomic_max_f(float* addr, float v)
{
    if (v >= 0.f) atomicMax((int*)addr, __float_as_int(v));
    else          atomicMin((unsigned int*)addr, __float_as_uint(v));
}

__global__ void gat_edge_logit(const int* __restrict__ ei, int E, int N, int heads,
                               const float* __restrict__ es, const float* __restrict__ ed,
                               float* __restrict__ eb, float* __restrict__ m)
{
    int gid = blockIdx.x * blockDim.x + threadIdx.x;
    int EE = E + N;
    if (gid >= EE * heads) return;
    int idx = gid / heads, hd = gid - idx * heads;
    int src, dst;
    if (idx < E) { src = ei[idx]; dst = ei[E + idx]; } else { src = dst = idx - E; }
    float e = es[src * heads + hd] + ed[dst * heads + hd];
    e = e > 0.f ? e : 0.2f * e;
    eb[gid] = e;
    atomic_max_f(&m[dst * heads + hd], e);
}

__global__ void gat_edge_expsum(const int* __restrict__ ei, int E, int N, int heads,
                                float* __restrict__ eb, const float* __restrict__ m,
                                float* __restrict__ s)
{
    int gid = blockIdx.x * blockDim.x + threadIdx.x;
    int EE = E + N;
    if (gid >= EE * heads) return;
    int idx = gid / heads, hd = gid - idx * heads;
    int dst = (idx < E) ? ei[E + idx] : idx - E;
    float e = __expf(eb[gid] - m[dst * heads + hd]);
    eb[gid] = e;
    atomicAdd(&s[dst * heads + hd], e);
}

template<int C, int VEC>
__global__ __launch_bounds__(256) void gat_accum_csr(
    const int* __restrict__ off, const int* __restrict__ eidx,
    const int* __restrict__ ei, int E,
    const float* __restrict__ eb, const float* __restrict__ s,
    const u16* __restrict__ feat, const float* __restrict__ bias,
    float* __restrict__ outf, u16* __restrict__ outb,
    int N, int heads, int HC, int nchunk)
{
    int gt = blockIdx.x * blockDim.x + threadIdx.x;
    int w = gt >> 6, lane = gt & 63;
    int dst = w / nchunk, chunk = w - dst * nchunk;
    if (dst >= N) return;
    int c0 = chunk * 64 * VEC + lane * VEC;
    if (c0 >= HC) return;
    int hh[VEC]; float sinv[VEC], acc[VEC];
#pragma unroll
    for (int v = 0; v < VEC; ++v) {
        int c = c0 + v;
        hh[v] = c / C;
        sinv[v] = __fdividef(1.f, s[dst * heads + hh[v]]);
        acc[v] = 0.f;
    }
    int e0 = off[dst], e1 = off[dst + 1];
    for (int p = e0; p < e1; ++p) {
        int j = eidx[p];
        int src = (j < E) ? ei[j] : (j - E);
        const u16* frp = feat + (size_t)src * HC + c0;
        float fv[VEC];
        if (VEC == 4) {
            uint2 pk = *(const uint2*)frp;
            fv[0] = bf2f((u16)(pk.x & 0xffff)); fv[1] = bf2f((u16)(pk.x >> 16));
            fv[2] = bf2f((u16)(pk.y & 0xffff)); fv[3] = bf2f((u16)(pk.y >> 16));
        } else {
            u32 pk = *(const u32*)frp;
            fv[0] = bf2f((u16)(pk & 0xffff)); fv[1] = bf2f((u16)(pk >> 16));
        }
#pragma unroll
        for (int v = 0; v < VEC; ++v)
            acc[v] += fv[v] * eb[(size_t)j * heads + hh[v]] * sinv[v];
    }
#pragma unroll
    for (int v = 0; v < VEC; ++v) {
        int c = c0 + v;
        float o = fmaxf(acc[v] + bias[c], 0.f);
        if (outf) outf[(size_t)dst * HC + c] = o;
        if (outb) outb[(size_t)dst * HC + c] = f2bf(o);
    }
}

__global__ void scatter_mean_accum(const float* __restrict__ x, const int* __restrict__ idx,
                                   float* __restrict__ ssum, float* __restrict__ cnt)
{
    int t = blockIdx.x * blockDim.x + threadIdx.x;
    if (t >= NTREE * HD) return;
    int n = t / HD, c = t - n * HD;
    int b = idx[n];
    atomicAdd(&ssum[b * HD + c], x[t]);
    if (c == 0) atomicAdd(&cnt[b], 1.f);
}

__global__ void fc_out(const float* __restrict__ ssum, const float* __restrict__ cnt,
                       const float* __restrict__ W, const float* __restrict__ b,
                       float* __restrict__ out)
{
    int t = threadIdx.x;                 // 512 threads
    int bb = t >> 2, j = t & 3;
    float inv = __fdividef(1.f, fmaxf(cnt[bb], 1.f));
    float acc = b[j];
    for (int k = 0; k < HD; ++k) acc += ssum[bb * HD + k] * inv * W[j * HD + k];
    out[t] = acc;
}

// ---------------------------------------------------------------------------
// Host launcher
// ---------------------------------------------------------------------------
extern "C" void kernel_launch(void* const* d_in, const int* in_sizes, int n_in,
                              void* d_out, int out_size, void* d_ws, size_t ws_size,
                              hipStream_t stream)
{
    const float* user_feats = (const float*)d_in[1];
    const int*   gnf        = (const int*)d_in[2];
    const int*   gei        = (const int*)d_in[3];
    const int*   tnf        = (const int*)d_in[4];
    const int*   tei        = (const int*)d_in[5];
    const int*   indices    = (const int*)d_in[6];
    const float* h0g        = (const float*)d_in[7];
    const float* h0t        = (const float*)d_in[8];
    const float* temb       = (const float*)d_in[9];
    const float* gW[2][4] = {{(const float*)d_in[10], (const float*)d_in[11], (const float*)d_in[12], (const float*)d_in[13]},
                             {(const float*)d_in[14], (const float*)d_in[15], (const float*)d_in[16], (const float*)d_in[17]}};
    const float* tW[2][4] = {{(const float*)d_in[18], (const float*)d_in[19], (const float*)d_in[20], (const float*)d_in[21]},
                             {(const float*)d_in[22], (const float*)d_in[23], (const float*)d_in[24], (const float*)d_in[25]}};
    const float* uW1 = (const float*)d_in[26]; const float* ub1 = (const float*)d_in[27];
    const float* uW2 = (const float*)d_in[28]; const float* ub2 = (const float*)d_in[29];
    const float* gc1W = (const float*)d_in[30]; const float* gc1as = (const float*)d_in[31];
    const float* gc1ad = (const float*)d_in[32]; const float* gc1b = (const float*)d_in[33];
    const float* gc2W = (const float*)d_in[34]; const float* gc2as = (const float*)d_in[35];
    const float* gc2ad = (const float*)d_in[36]; const float* gc2b = (const float*)d_in[37];
    const float* tc1W = (const float*)d_in[38]; const float* tc1as = (const float*)d_in[39];
    const float* tc1ad = (const float*)d_in[40]; const float* tc1b = (const float*)d_in[41];
    const float* tc2W = (const float*)d_in[42]; const float* tc2as = (const float*)d_in[43];
    const float* tc2ad = (const float*)d_in[44]; const float* tc2b = (const float*)d_in[45];
    const float* fcW = (const float*)d_in[46]; const float* fcb = (const float*)d_in[47];
    float* out = (float*)d_out;

    char* ws = (char*)d_ws;
    const size_t NEED = 226500000;
    if (ws_size < NEED) return;

    // ---- workspace layout (decimal byte offsets) ----
    float* XGF    = (float*)(ws + 0);            // 12 MB xg_final fp32 [NG][100]
    u16*   TEMB_B = (u16*)(ws + 12000000);       // 12.8 MB [VOC][128]
    u16*   ETAB_G = (u16*)(ws + 25000000);       // 35.2 MB [VOC][352]
    u16*   ETAB_T = (u16*)(ws + 60400000);       // 35.2 MB
    u16*   GH1B   = (u16*)(ws + 96000000);       // 2.56 MB [NTG][128]
    u16*   TH1B   = (u16*)(ws + 98600000);       // 7.68 MB [NTREE][128]
    float* UE     = (float*)(ws + 106400000);    // 8 MB
    float* HID    = (float*)(ws + 114400000);    // 8 MB
    u16*   WARENA = (u16*)(ws + 122400000);      // ~0.94 MB
    int*   GOFF   = (int*)(ws + 123600000);
    int*   GCUR   = (int*)(ws + 123800000);
    int*   GCNT   = (int*)(ws + 124000000);
    int*   GEIDX  = (int*)(ws + 124200000);      // 0.92 MB
    int*   TOFF   = (int*)(ws + 125200000);
    int*   TCUR   = (int*)(ws + 125400000);
    int*   TCNT   = (int*)(ws + 125600000);
    int*   TEIDX  = (int*)(ws + 125800000);      // 0.36 MB
    float* ESB    = (float*)(ws + 126200000);
    float* EDB    = (float*)(ws + 127200000);
    float* MB     = (float*)(ws + 128200000);
    float* SB     = (float*)(ws + 129200000);
    float* EBB    = (float*)(ws + 130200000);    // 7.36 MB
    float* SSUM   = (float*)(ws + 137600000);
    float* SCNT   = (float*)(ws + 137700000);
    u16*   XG_B   = (u16*)(ws + 138000000);      // 7.68 MB [NG][128]
    u16*   GFEAT1 = (u16*)(ws + 146000000);      // 30.72 MB [NG][512]
    u16*   GOUT1B = (u16*)(ws + 177000000);      // 30.72 MB
    u16*   GFEAT2 = (u16*)(ws + 208000000);      // 6 MB [NG][100]
    u16*   TFEAT1 = (u16*)(ws + 25000000);       // 48 MB [NTREE][800] (overlays Etabs, dead)
    u16*   TOUT1B = (u16*)(ws + 146000000);      // 48 MB (overlays GFEAT1/GOUT1B, dead)
    u16*   TFEAT2 = (u16*)(ws + 208000000);      // 6 MB (overlay GFEAT2, dead)
    float* XOUT2  = (float*)(ws + 214400000);    // 12 MB -> 226.4 MB

    // weight arena slots (u16 element offsets); each GRU W = [320][128]
    u16* gWHH0 = WARENA + 0;
    u16* gWIH1 = WARENA + 40960;
    u16* gWHH1 = WARENA + 81920;
    u16* tWHH0 = WARENA + 122880;
    u16* tWIH1 = WARENA + 163840;
    u16* tWHH1 = WARENA + 204800;
    u16* W_IH0 = WARENA + 245760;    // [320][128] scratch for Etab builds
    u16* W_G1  = WARENA + 286720;    // up to [800][128]
    u16* W_G2  = WARENA + 389120;    // up to [100][800]

    auto cvt = [&](const float* src, u16* dst, int M, int Mp, int K, int ldk,
                   const float* app = nullptr, int appone = 0) {
        convert_pad2<<<((size_t)Mp * ldk + 255) / 256, 256, 0, stream>>>(
            src, dst, M, Mp, K, ldk, app, appone);
    };
    auto mfma = [&](const u16* A, int lda, const u16* W, int ldw,
                    float* Cf, u16* Cb, int ldc, int M, int N, int Kt, int seg = 0) {
        dim3 grid((M + 63) / 64, (N + 63) / 64, 1);
        gemm_mfma<<<grid, 256, 0, stream>>>(A, W, Cf, Cb, M, N, Kt, lda, ldw, ldc, seg);
    };
    auto csr_build = [&](const int* ei, int E, int N, int* cnt, int* off, int* cur, int* eidx) {
        hipMemsetAsync(cnt, 0, (size_t)N * 4, stream);
        csr_count<<<(E + N + 255) / 256, 256, 0, stream>>>(ei, E, N, cnt);
        csr_scan<<<1, 256, 0, stream>>>(cnt, off, cur, N);
        csr_scatter<<<(E + N + 255) / 256, 256, 0, stream>>>(ei, E, N, cur, eidx);
    };
    auto gat_pre = [&](const u16* feat, int N, int heads, int C,
                       const float* asrc, const float* adst, const int* ei, int E) {
        gat_es_ed<<<(N * heads + 255) / 256, 256, 0, stream>>>(feat, asrc, adst, ESB, EDB, N, heads, C);
        hipMemsetAsync(MB, 0xFF, (size_t)N * heads * 4, stream);
        hipMemsetAsync(SB, 0, (size_t)N * heads * 4, stream);
        int EE = E + N;
        gat_edge_logit<<<(EE * heads + 255) / 256, 256, 0, stream>>>(ei, E, N, heads, ESB, EDB, EBB, MB);
        gat_edge_expsum<<<(EE * heads + 255) / 256, 256, 0, stream>>>(ei, E, N, heads, EBB, MB, SB);
    };

    // ---- 1. user embed (fp32) ----
    {
        dim3 g1((NU + 63) / 64, (HD + 63) / 64, 1);
        gemm_nt<<<g1, 256, 0, stream>>>(user_feats, uW1, ub1, HID, NU, HD, 9, 1);
        gemm_nt<<<g1, 256, 0, stream>>>(HID, uW2, ub2, UE, NU, HD, HD, 0);
    }

    // ---- 2. converts (+bias fold into col 100) + Etab builds ----
    cvt(temb, TEMB_B, VOC, VOC, HD, 128, nullptr, 1);           // col100 = 1
    cvt(gW[0][1], gWHH0, 300, 320, HD, 128, gW[0][3]);          // + bhh0
    cvt(gW[1][0], gWIH1, 300, 320, HD, 128, gW[1][2]);          // + bih1
    cvt(gW[1][1], gWHH1, 300, 320, HD, 128, gW[1][3]);          // + bhh1
    cvt(tW[0][1], tWHH0, 300, 320, HD, 128, tW[0][3]);
    cvt(tW[1][0], tWIH1, 300, 320, HD, 128, tW[1][2]);
    cvt(tW[1][1], tWHH1, 300, 320, HD, 128, tW[1][3]);
    cvt(gW[0][0], W_IH0, 300, 320, HD, 128, gW[0][2]);          // + bih0
    mfma(TEMB_B, 128, W_IH0, 128, nullptr, ETAB_G, ESTR, VOC, 300, 4, 1);
    cvt(tW[0][0], W_IH0, 300, 320, HD, 128, tW[0][2]);
    mfma(TEMB_B, 128, W_IH0, 128, nullptr, ETAB_T, ESTR, VOC, 300, 4, 1);

    // CSR for both graphs
    csr_build(gei, EG, NG, GCNT, GOFF, GCUR, GEIDX);
    csr_build(tei, ET, NTREE, TCNT, TOFF, TCUR, TEIDX);

    // ---- 3. combined wave-autonomous GRU (both branches, one launch) ----
    {
        GruProb Pg = { ETAB_G, gnf, h0g, gWHH0, gWIH1, gWHH1, GH1B, NTG };
        GruProb Pt = { ETAB_T, tnf, h0t, tWHH0, tWIH1, tWHH1, TH1B, NTREE };
        int gwv = NTG / 16;      // 625
        int twv = NTREE / 16;    // 1875
        gru_fused3<<<gwv + twv, 64, 0, stream>>>(Pg, Pt, gwv);
    }

    // ---- 4. graph GAT chain ----
    build_xg_bf<<<(NG * 128 + 255) / 256, 256, 0, stream>>>(GH1B, UE, XG_B);
    cvt(gc1W, W_G1, 512, 512, HD, 128);
    cvt(gc2W, W_G2, 100, 100, 512, 512);
    {   // graph GAT1: 8 heads x 64
        mfma(XG_B, 128, W_G1, 128, nullptr, GFEAT1, 512, NG, 512, 4);
        gat_pre(GFEAT1, NG, 8, 64, gc1as, gc1ad, gei, EG);
        int waves = NG * 2;
        gat_accum_csr<64, 4><<<(waves + 3) / 4, 256, 0, stream>>>(
            GOFF, GEIDX, gei, EG, EBB, SB, GFEAT1, gc1b, nullptr, GOUT1B, NG, 8, 512, 2);
    }
    {   // graph GAT2: 1 head x 100
        mfma(GOUT1B, 512, W_G2, 512, nullptr, GFEAT2, 100, NG, 100, 16);
        gat_pre(GFEAT2, NG, 1, 100, gc2as, gc2ad, gei, EG);
        int waves = NG;
        gat_accum_csr<100, 2><<<(waves + 3) / 4, 256, 0, stream>>>(
            GOFF, GEIDX, gei, EG, EBB, SB, GFEAT2, gc2b, XGF, nullptr, NG, 1, 100, 1);
    }

    // ---- 5. tree GAT chain ----
    set_roots<<<(NB * HD + 255) / 256, 256, 0, stream>>>(XGF, TH1B);
    cvt(tc1W, W_G1, 800, 800, HD, 128);
    cvt(tc2W, W_G2, 100, 100, 800, 800);
    {   // tree GAT1: 8 heads x 100
        mfma(TH1B, 128, W_G1, 128, nullptr, TFEAT1, 800, NTREE, 800, 4);
        gat_pre(TFEAT1, NTREE, 8, 100, tc1as, tc1ad, tei, ET);
        int waves = NTREE * 4;
        gat_accum_csr<100, 4><<<(waves + 3) / 4, 256, 0, stream>>>(
            TOFF, TEIDX, tei, ET, EBB, SB, TFEAT1, tc1b, nullptr, TOUT1B, NTREE, 8, 800, 4);
    }
    {   // tree GAT2: 1 head x 100
        mfma(TOUT1B, 800, W_G2, 800, nullptr, TFEAT2, 100, NTREE, 100, 25);
        gat_pre(TFEAT2, NTREE, 1, 100, tc2as, tc2ad, tei, ET);
        int waves = NTREE;
        gat_accum_csr<100, 2><<<(waves + 3) / 4, 256, 0, stream>>>(
            TOFF, TEIDX, tei, ET, EBB, SB, TFEAT2, tc2b, XOUT2, nullptr, NTREE, 1, 100, 1);
    }

    // ---- 6. scatter_mean + classifier ----
    hipMemsetAsync(SSUM, 0, (size_t)NB * HD * 4, stream);
    hipMemsetAsync(SCNT, 0, (size_t)NB * 4, stream);
    scatter_mean_accum<<<(NTREE * HD + 255) / 256, 256, 0, stream>>>(XOUT2, indices, SSUM, SCNT);
    fc_out<<<1, 512, 0, stream>>>(SSUM, SCNT, fcW, fcb, out);
}

// Round 7
// 2896.306 us; speedup vs baseline: 1.1880x; 1.1880x over previous
//
#include <hip/hip_runtime.h>

// ---------------------------------------------------------------------------
// Problem constants
// ---------------------------------------------------------------------------
#define NB    128
#define HD    100
#define NU    20000
#define NTG   10000
#define NTREE 30000
#define NG    30000
#define TT    20
#define EG    200000
#define ET    60000
#define VOC   50000

#define ESTR  304   // Etab row stride (u16): 608 B, 16B-aligned, = 38 uint4
#define GASTR 416   // gate LDS row stride (u16): cols 0..299 gates, 300..399 hn

typedef unsigned short u16;
typedef unsigned int   u32;
typedef __attribute__((ext_vector_type(8))) short short8;
typedef __attribute__((ext_vector_type(4))) float floatx4;

__device__ __forceinline__ float sigmoidf_(float x) {
    return __fdividef(1.f, 1.f + __expf(-x));
}
__device__ __forceinline__ float tanhf_(float x) {
    return 1.f - __fdividef(2.f, __expf(2.f * x) + 1.f);
}
__device__ __forceinline__ u16 f2bf(float f) {
    u32 u = __float_as_uint(f);
    u32 r = (u + 0x7fffu + ((u >> 16) & 1u)) >> 16;
    return (u16)r;
}
__device__ __forceinline__ float bf2f(u16 h) {
    return __uint_as_float(((u32)h) << 16);
}

// ---------------------------------------------------------------------------
// Fused 2-layer GRU v4: 256 threads own 32 rows for all TT steps.
// - Etab x-gates staged per step into LDS by the whole block (aligned uint4,
//   issued before GEMM0, consumed after one covered latency).
// - node ids preloaded once into LDS.
// - h carry in registers (combine mapping) + bf16 LDS mirror (GEMM mapping).
// - biases folded into the K=100 slot (h col100 == 1, W col100 == bias).
// LDS ~66 KB -> 2 blocks/CU (8 waves/CU from independent blocks).
// ---------------------------------------------------------------------------
struct GruProb {
    const u16*   Etab;     // [VOC][304] (includes bih0)
    const int*   nodes;    // [M][TT]
    const float* h0;       // [2][M][100] fp32
    const u16*   Whh0;     // [320][128] (col100 = bhh0)
    const u16*   Wih1;     // (col100 = bih1)
    const u16*   Whh1;     // (col100 = bhh1)
    u16*         hout;     // [M][128]
    int          M;
};

__global__ __launch_bounds__(256) void gru_fused4(GruProb Pg, GruProb Pt, int gblocks)
{
    const bool isg = (int)blockIdx.x < gblocks;
    const GruProb P = isg ? Pg : Pt;
    const int bx = isg ? blockIdx.x : blockIdx.x - gblocks;
    const int M  = P.M;
    const int m0 = bx * 32;

    __shared__ u16 h0b[32 * 136];
    __shared__ u16 h1b[32 * 136];
    __shared__ u16 GA[32 * GASTR];
    __shared__ u16 Xs[32 * ESTR];     // staged Etab rows for current step
    __shared__ int nidL[32 * TT];

    const int tid  = threadIdx.x;
    const int wave = tid >> 6, lane = tid & 63;
    const int fr   = lane & 15, quad = lane >> 4;

    // combine mapping: 8 threads per row, 13-col runs
    const int crow = tid >> 3;
    const int cgm  = m0 + crow;
    const int c0   = (tid & 7) * 13;
    const int L    = (c0 < 100) ? ((100 - c0 < 13) ? (100 - c0) : 13) : 0;
    const bool cok = (cgm < M);

    // ---- init LDS ----
    for (int i = tid; i < 32 * 136; i += 256) { h0b[i] = 0; h1b[i] = 0; }
    for (int i = tid; i < 32 * TT; i += 256) {
        int r = i / TT, t = i - r * TT;
        int gm = m0 + r;
        nidL[i] = (gm < M) ? P.nodes[(size_t)gm * TT + t] : 0;
    }
    __syncthreads();
    if (tid < 32) {
        h0b[tid * 136 + 100] = 0x3F80;   // 1.0 bias slot
        h1b[tid * 136 + 100] = 0x3F80;
    }
    // h carry in registers
    float h0f[13], h1f[13];
#pragma unroll
    for (int j = 0; j < 13; ++j) { h0f[j] = 0.f; h1f[j] = 0.f; }
    if (cok) {
#pragma unroll
        for (int j = 0; j < 13; ++j) if (j < L) {
            int c = c0 + j;
            float v0 = P.h0[(size_t)cgm * 100 + c];
            float v1 = P.h0[(size_t)(M + cgm) * 100 + c];
            h0f[j] = v0; h1f[j] = v1;
            h0b[crow * 136 + c] = f2bf(v0);
            h1b[crow * 136 + c] = f2bf(v1);
        }
    }
    __syncthreads();

    for (int t = 0; t < TT; ++t) {
        // ---- 1. issue Etab staging loads (32 rows x 38 uint4 = 1216) ----
        uint4 xr[5];
        int xidx[5];
#pragma unroll
        for (int it = 0; it < 5; ++it) {
            int idx = tid + it * 256;
            xidx[it] = idx;
            if (idx < 1216) {
                int row = idx / 38, off = idx - row * 38;
                const u16* ep = P.Etab + (size_t)nidL[row * TT + t] * ESTR + off * 8;
                xr[it] = *(const uint4*)ep;
            }
        }

        // ---- 2. GEMM0: Gh0 = h0 @ Whh0^T -> GA cols 0..299 ----
#pragma unroll
        for (int rt = 0; rt < 2; ++rt) {
            short8 a[4];
#pragma unroll
            for (int kk = 0; kk < 4; ++kk)
                a[kk] = *(const short8*)&h0b[(rt * 16 + fr) * 136 + kk * 32 + quad * 8];
#pragma unroll
            for (int s = 0; s < 5; ++s) {
                int ct = wave + 4 * s;
                if (ct >= 19) continue;
                const u16* wp = P.Whh0 + (size_t)(ct * 16 + fr) * 128 + 8 * quad;
                floatx4 acc = {0.f, 0.f, 0.f, 0.f};
#pragma unroll
                for (int kk = 0; kk < 4; ++kk)
                    acc = __builtin_amdgcn_mfma_f32_16x16x32_bf16(
                        a[kk], *(const short8*)(wp + kk * 32), acc, 0, 0, 0);
                int col = ct * 16 + fr;
                if (col < 300) {
                    int rbase = rt * 16 + quad * 4;
#pragma unroll
                    for (int r = 0; r < 4; ++r)
                        GA[(rbase + r) * GASTR + col] = f2bf(acc[r]);
                }
            }
        }

        // ---- 3. park staged Etab into LDS ----
#pragma unroll
        for (int it = 0; it < 5; ++it) {
            if (xidx[it] < 1216)
                *(uint4*)&Xs[xidx[it] * 8] = xr[it];
        }
        __syncthreads();

        // ---- 4. combine layer 0 ----
        if (cok) {
#pragma unroll
            for (int j = 0; j < 13; ++j) if (j < L) {
                int c = c0 + j;
                float xrg = bf2f(Xs[crow * ESTR + c]);
                float xzg = bf2f(Xs[crow * ESTR + 100 + c]);
                float xng = bf2f(Xs[crow * ESTR + 200 + c]);
                float hrg = bf2f(GA[crow * GASTR + c]);
                float hzg = bf2f(GA[crow * GASTR + 100 + c]);
                float hng = bf2f(GA[crow * GASTR + 200 + c]);
                float r  = sigmoidf_(xrg + hrg);
                float zz = sigmoidf_(xzg + hzg);
                float ng = tanhf_(xng + r * hng);
                float o  = (1.f - zz) * ng + zz * h0f[j];
                h0f[j] = o;
                h0b[crow * 136 + c] = f2bf(o);
            }
        }
        __syncthreads();

        // ---- 5. GEMM1: Gx1 = h0@Wih1^T, Gh1 = h1@Whh1^T ----
        // cols<200: store ax+ah; cols 200..299: ax -> GA[col], ah -> GA[100+col]
#pragma unroll
        for (int rt = 0; rt < 2; ++rt) {
            short8 a0[4], a1[4];
#pragma unroll
            for (int kk = 0; kk < 4; ++kk) {
                a0[kk] = *(const short8*)&h0b[(rt * 16 + fr) * 136 + kk * 32 + quad * 8];
                a1[kk] = *(const short8*)&h1b[(rt * 16 + fr) * 136 + kk * 32 + quad * 8];
            }
#pragma unroll
            for (int s = 0; s < 5; ++s) {
                int ct = wave + 4 * s;
                if (ct >= 19) continue;
                const u16* wpx = P.Wih1 + (size_t)(ct * 16 + fr) * 128 + 8 * quad;
                const u16* wph = P.Whh1 + (size_t)(ct * 16 + fr) * 128 + 8 * quad;
                floatx4 ax = {0.f, 0.f, 0.f, 0.f};
                floatx4 ah = {0.f, 0.f, 0.f, 0.f};
#pragma unroll
                for (int kk = 0; kk < 4; ++kk) {
                    ax = __builtin_amdgcn_mfma_f32_16x16x32_bf16(
                        a0[kk], *(const short8*)(wpx + kk * 32), ax, 0, 0, 0);
                    ah = __builtin_amdgcn_mfma_f32_16x16x32_bf16(
                        a1[kk], *(const short8*)(wph + kk * 32), ah, 0, 0, 0);
                }
                int col = ct * 16 + fr;
                if (col < 300) {
                    int rbase = rt * 16 + quad * 4;
                    if (col < 200) {
#pragma unroll
                        for (int r = 0; r < 4; ++r)
                            GA[(rbase + r) * GASTR + col] = f2bf(ax[r] + ah[r]);
                    } else {
#pragma unroll
                        for (int r = 0; r < 4; ++r) {
                            GA[(rbase + r) * GASTR + col] = f2bf(ax[r]);
                            GA[(rbase + r) * GASTR + 100 + col] = f2bf(ah[r]);
                        }
                    }
                }
            }
        }
        __syncthreads();

        // ---- 6. combine layer 1 ----
        if (cok) {
#pragma unroll
            for (int j = 0; j < 13; ++j) if (j < L) {
                int c = c0 + j;
                float sr_ = bf2f(GA[crow * GASTR + c]);
                float sz_ = bf2f(GA[crow * GASTR + 100 + c]);
                float xn_ = bf2f(GA[crow * GASTR + 200 + c]);
                float hn_ = bf2f(GA[crow * GASTR + 300 + c]);
                float r  = sigmoidf_(sr_);
                float zz = sigmoidf_(sz_);
                float ng = tanhf_(xn_ + r * hn_);
                float o  = (1.f - zz) * ng + zz * h1f[j];
                h1f[j] = o;
                h1b[crow * 136 + c] = f2bf(o);
            }
        }
        __syncthreads();
    }

    // ---- write final top-layer hidden, bf16 [M][128] ----
    for (int i = tid; i < 32 * 128; i += 256) {
        int row = i >> 7, c = i & 127;
        int gm = m0 + row;
        if (gm < M)
            P.hout[(size_t)gm * 128 + c] = h1b[row * 136 + c];
    }
}

// ---------------------------------------------------------------------------
// bf16 MFMA GEMM (Etab build + GAT feature GEMMs)
// ---------------------------------------------------------------------------
#define LDST 40
__global__ __launch_bounds__(256) void gemm_mfma(
    const u16* __restrict__ A, const u16* __restrict__ B,
    float* __restrict__ Cf, u16* __restrict__ Cb,
    int M, int N, int Kt, int lda, int ldw, int ldc)
{
    const int m0 = blockIdx.x * 64;
    if (m0 >= M) return;
    const int n0 = blockIdx.y * 64;

    __shared__ u16 Als[64 * LDST];
    __shared__ u16 Wls[64 * LDST];

    const int tid  = threadIdx.x;
    const int wave = tid >> 6, lane = tid & 63;
    const int row  = tid >> 2, part = (tid & 3) * 8;
    const int fr   = lane & 15, quad = lane >> 4;

    floatx4 acc[4];
#pragma unroll
    for (int t = 0; t < 4; ++t) acc[t] = (floatx4){0.f, 0.f, 0.f, 0.f};

    const int am = m0 + row;  const bool aok = am < M;
    const int wn = n0 + row;  const bool wok = wn < N;
    const uint4 z4 = {0u, 0u, 0u, 0u};

    for (int kk = 0; kk < Kt; ++kk) {
        uint4 av = aok ? *(const uint4*)(A + (size_t)am * lda + kk * 32 + part) : z4;
        uint4 wv = wok ? *(const uint4*)(B + (size_t)wn * ldw + kk * 32 + part) : z4;
        __syncthreads();
        *(uint4*)&Als[row * LDST + part] = av;
        *(uint4*)&Wls[row * LDST + part] = wv;
        __syncthreads();
        short8 af = *(const short8*)&Als[((wave << 4) + fr) * LDST + quad * 8];
#pragma unroll
        for (int t = 0; t < 4; ++t) {
            short8 bf = *(const short8*)&Wls[((t << 4) + fr) * LDST + quad * 8];
            acc[t] = __builtin_amdgcn_mfma_f32_16x16x32_bf16(af, bf, acc[t], 0, 0, 0);
        }
    }

    const int orow0 = m0 + (wave << 4) + quad * 4;
#pragma unroll
    for (int t = 0; t < 4; ++t) {
        int col = n0 + (t << 4) + fr;
        if (col >= N) continue;
#pragma unroll
        for (int r = 0; r < 4; ++r) {
            int mr = orow0 + r;
            if (mr >= M) continue;
            float v = acc[t][r];
            if (Cf) Cf[(size_t)mr * ldc + col] = v;
            if (Cb) Cb[(size_t)mr * ldc + col] = f2bf(v);
        }
    }
}

// ---------------------------------------------------------------------------
// fp32 tiled GEMM (user-embed MLP only)
// ---------------------------------------------------------------------------
__global__ __launch_bounds__(256) void gemm_nt(
    const float* __restrict__ A, const float* __restrict__ W,
    const float* __restrict__ bias, float* __restrict__ C,
    int M, int N, int K, int relu)
{
    const int m0 = blockIdx.x * 64;
    const int n0 = blockIdx.y * 64;
    __shared__ float As[20][68];
    __shared__ float Ws[20][68];
    const int tid = threadIdx.x;
    const int r0 = (tid >> 4) * 4;
    const int c0 = (tid & 15) * 4;
    int sr[5], sk[5];
#pragma unroll
    for (int it = 0; it < 5; ++it) {
        int idx = tid + it * 256;
        sr[it] = idx / 20; sk[it] = idx - sr[it] * 20;
    }
    float acc[4][4];
#pragma unroll
    for (int i = 0; i < 4; ++i)
#pragma unroll
        for (int j = 0; j < 4; ++j) acc[i][j] = 0.f;
    const int nch = (K + 19) / 20;
    for (int ch = 0; ch < nch; ++ch) {
        const int k0 = ch * 20;
#pragma unroll
        for (int it = 0; it < 5; ++it) {
            int m = m0 + sr[it], k = k0 + sk[it];
            float va = 0.f, vw = 0.f;
            if (k < K) {
                if (m < M) va = A[(size_t)m * K + k];
                int n = n0 + sr[it];
                if (n < N) vw = W[(size_t)n * K + k];
            }
            As[sk[it]][sr[it]] = va;
            Ws[sk[it]][sr[it]] = vw;
        }
        __syncthreads();
#pragma unroll
        for (int kkk = 0; kkk < 20; ++kkk) {
            float4 a = *(const float4*)&As[kkk][r0];
            float4 w = *(const float4*)&Ws[kkk][c0];
            float av[4] = {a.x, a.y, a.z, a.w};
            float wv[4] = {w.x, w.y, w.z, w.w};
#pragma unroll
            for (int i = 0; i < 4; ++i)
#pragma unroll
                for (int j = 0; j < 4; ++j)
                    acc[i][j] = fmaf(av[i], wv[j], acc[i][j]);
        }
        __syncthreads();
    }
#pragma unroll
    for (int i = 0; i < 4; ++i) {
        int m = m0 + r0 + i;
        if (m >= M) continue;
#pragma unroll
        for (int j = 0; j < 4; ++j) {
            int n = n0 + c0 + j;
            if (n >= N) continue;
            float v = acc[i][j] + (bias ? bias[n] : 0.f);
            if (relu) v = fmaxf(v, 0.f);
            C[(size_t)m * N + n] = v;
        }
    }
}

// fp32 [M][K] -> bf16 [Mp][ldk]; col K..ldk zero, except col 100 gets
// app[n] (if app) or 1.0 (if appone) — the K-slot bias fold.
__global__ void convert_pad2(const float* __restrict__ src, u16* __restrict__ dst,
                             int M, int Mp, int K, int ldk,
                             const float* __restrict__ app, int appone)
{
    int t = blockIdx.x * blockDim.x + threadIdx.x;
    if (t >= Mp * ldk) return;
    int n = t / ldk, c = t - n * ldk;
    u16 o = 0;
    if (n < M) {
        if (c < K) o = f2bf(src[(size_t)n * K + c]);
        else if (c == 100) {
            if (app) o = f2bf(app[n]);
            else if (appone) o = 0x3F80;
        }
    }
    dst[t] = o;
}

// xg (bf16 [NG][128]) = concat(hg[:128], ue, hg[128:])
__global__ void build_xg_bf(const u16* __restrict__ hgb, const float* __restrict__ ue,
                            u16* __restrict__ xgb)
{
    int t = blockIdx.x * blockDim.x + threadIdx.x;
    if (t >= NG * 128) return;
    int n = t >> 7, c = t & 127;
    u16 o = 0;
    if (n < NB)           o = hgb[n * 128 + c];
    else if (n < NB + NU) { if (c < HD) o = f2bf(ue[(size_t)(n - NB) * HD + c]); }
    else                  o = hgb[(size_t)(n - NU) * 128 + c];
    xgb[t] = o;
}

// tree roots: hb rows[0:128) <- xg_final fp32
__global__ void set_roots(const float* __restrict__ src, u16* __restrict__ hb)
{
    int t = blockIdx.x * blockDim.x + threadIdx.x;
    if (t >= NB * HD) return;
    int n = t / HD, c = t - n * HD;
    hb[(size_t)n * 128 + c] = f2bf(src[t]);
}

// ---------------------------------------------------------------------------
// CSR build
// ---------------------------------------------------------------------------
__global__ void csr_count(const int* __restrict__ ei, int E, int N, int* __restrict__ cnt)
{
    int e = blockIdx.x * blockDim.x + threadIdx.x;
    if (e >= E + N) return;
    int dst = (e < E) ? ei[E + e] : e - E;
    atomicAdd(&cnt[dst], 1);
}

__global__ void csr_scan(const int* __restrict__ cnt, int* __restrict__ off,
                         int* __restrict__ cur, int N)
{
    __shared__ int part[256];
    const int tid = threadIdx.x;
    const int per = (N + 255) / 256;
    const int i0 = tid * per;
    const int i1 = min(i0 + per, N);
    int s = 0;
    for (int i = i0; i < i1; ++i) s += cnt[i];
    part[tid] = s;
    __syncthreads();
    for (int o = 1; o < 256; o <<= 1) {
        int u = (tid >= o) ? part[tid - o] : 0;
        __syncthreads();
        part[tid] += u;
        __syncthreads();
    }
    int base = part[tid] - s;
    for (int i = i0; i < i1; ++i) {
        off[i] = base; cur[i] = base;
        base += cnt[i];
    }
    if (tid == 255) off[N] = part[255];
}

__global__ void csr_scatter(const int* __restrict__ ei, int E, int N,
                            int* __restrict__ cur, int* __restrict__ eidx)
{
    int e = blockIdx.x * blockDim.x + threadIdx.x;
    if (e >= E + N) return;
    int dst = (e < E) ? ei[E + e] : e - E;
    int pos = atomicAdd(&cur[dst], 1);
    eidx[pos] = e;
}

// ---------------------------------------------------------------------------
// GAT pieces (feat is bf16)
// ---------------------------------------------------------------------------
__global__ void gat_es_ed(const u16* __restrict__ feat, const float* __restrict__ asrc,
                          const float* __restrict__ adst, float* __restrict__ es,
                          float* __restrict__ ed, int N, int heads, int C)
{
    int gid = blockIdx.x * blockDim.x + threadIdx.x;
    if (gid >= N * heads) return;
    int n = gid / heads, hd = gid - n * heads;
    const u16* hp = feat + ((size_t)n * heads + hd) * C;
    const float* as = asrc + (size_t)hd * C;
    const float* ad = adst + (size_t)hd * C;
    float s1 = 0.f, s2 = 0.f;
    for (int c = 0; c < C; c += 4) {
        uint2 pk = *(const uint2*)(hp + c);
        float v0 = bf2f((u16)(pk.x & 0xffff)), v1 = bf2f((u16)(pk.x >> 16));
        float v2 = bf2f((u16)(pk.y & 0xffff)), v3 = bf2f((u16)(pk.y >> 16));
        s1 += v0 * as[c] + v1 * as[c + 1] + v2 * as[c + 2] + v3 * as[c + 3];
        s2 += v0 * ad[c] + v1 * ad[c + 1] + v2 * ad[c + 2] + v3 * ad[c + 3];
    }
    es[gid] = s1; ed[gid] = s2;
}

__device__ __forceinline__ void atomic_max_f(float* addr, float v)
{
    if (v >= 0.f) atomicMax((int*)addr, __float_as_int(v));
    else          atomicMin((unsigned int*)addr, __float_as_uint(v));
}

__global__ void gat_edge_logit(const int* __restrict__ ei, int E, int N, int heads,
                               const float* __restrict__ es, const float* __restrict__ ed,
                               float* __restrict__ eb, float* __restrict__ m)
{
    int gid = blockIdx.x * blockDim.x + threadIdx.x;
    int EE = E + N;
    if (gid >= EE * heads) return;
    int idx = gid / heads, hd = gid - idx * heads;
    int src, dst;
    if (idx < E) { src = ei[idx]; dst = ei[E + idx]; } else { src = dst = idx - E; }
    float e = es[src * heads + hd] + ed[dst * heads + hd];
    e = e > 0.f ? e : 0.2f * e;
    eb[gid] = e;
    atomic_max_f(&m[dst * heads + hd], e);
}

__global__ void gat_edge_expsum(const int* __restrict__ ei, int E, int N, int heads,
                                float* __restrict__ eb, const float* __restrict__ m,
                                float* __restrict__ s)
{
    int gid = blockIdx.x * blockDim.x + threadIdx.x;
    int EE = E + N;
    if (gid >= EE * heads) return;
    int idx = gid / heads, hd = gid - idx * heads;
    int dst = (idx < E) ? ei[E + idx] : idx - E;
    float e = __expf(eb[gid] - m[dst * heads + hd]);
    eb[gid] = e;
    atomicAdd(&s[dst * heads + hd], e);
}

template<int C, int VEC>
__global__ __launch_bounds__(256) void gat_accum_csr(
    const int* __restrict__ off, const int* __restrict__ eidx,
    const int* __restrict__ ei, int E,
    const float* __restrict__ eb, const float* __restrict__ s,
    const u16* __restrict__ feat, const float* __restrict__ bias,
    float* __restrict__ outf, u16* __restrict__ outb,
    int N, int heads, int HC, int nchunk)
{
    int gt = blockIdx.x * blockDim.x + threadIdx.x;
    int w = gt >> 6, lane = gt & 63;
    int dst = w / nchunk, chunk = w - dst * nchunk;
    if (dst >= N) return;
    int c0 = chunk * 64 * VEC + lane * VEC;
    if (c0 >= HC) return;
    int hh[VEC]; float sinv[VEC], acc[VEC];
#pragma unroll
    for (int v = 0; v < VEC; ++v) {
        int c = c0 + v;
        hh[v] = c / C;
        sinv[v] = __fdividef(1.f, s[dst * heads + hh[v]]);
        acc[v] = 0.f;
    }
    int e0 = off[dst], e1 = off[dst + 1];
    for (int p = e0; p < e1; ++p) {
        int j = eidx[p];
        int src = (j < E) ? ei[j] : (j - E);
        const u16* frp = feat + (size_t)src * HC + c0;
        float fv[VEC];
        if (VEC == 4) {
            uint2 pk = *(const uint2*)frp;
            fv[0] = bf2f((u16)(pk.x & 0xffff)); fv[1] = bf2f((u16)(pk.x >> 16));
            fv[2] = bf2f((u16)(pk.y & 0xffff)); fv[3] = bf2f((u16)(pk.y >> 16));
        } else {
            u32 pk = *(const u32*)frp;
            fv[0] = bf2f((u16)(pk & 0xffff)); fv[1] = bf2f((u16)(pk >> 16));
        }
#pragma unroll
        for (int v = 0; v < VEC; ++v)
            acc[v] += fv[v] * eb[(size_t)j * heads + hh[v]] * sinv[v];
    }
#pragma unroll
    for (int v = 0; v < VEC; ++v) {
        int c = c0 + v;
        float o = fmaxf(acc[v] + bias[c], 0.f);
        if (outf) outf[(size_t)dst * HC + c] = o;
        if (outb) outb[(size_t)dst * HC + c] = f2bf(o);
    }
}

__global__ void scatter_mean_accum(const float* __restrict__ x, const int* __restrict__ idx,
                                   float* __restrict__ ssum, float* __restrict__ cnt)
{
    int t = blockIdx.x * blockDim.x + threadIdx.x;
    if (t >= NTREE * HD) return;
    int n = t / HD, c = t - n * HD;
    int b = idx[n];
    atomicAdd(&ssum[b * HD + c], x[t]);
    if (c == 0) atomicAdd(&cnt[b], 1.f);
}

__global__ void fc_out(const float* __restrict__ ssum, const float* __restrict__ cnt,
                       const float* __restrict__ W, const float* __restrict__ b,
                       float* __restrict__ out)
{
    int t = threadIdx.x;                 // 512 threads
    int bb = t >> 2, j = t & 3;
    float inv = __fdividef(1.f, fmaxf(cnt[bb], 1.f));
    float acc = b[j];
    for (int k = 0; k < HD; ++k) acc += ssum[bb * HD + k] * inv * W[j * HD + k];
    out[t] = acc;
}

// ---------------------------------------------------------------------------
// Host launcher
// ---------------------------------------------------------------------------
extern "C" void kernel_launch(void* const* d_in, const int* in_sizes, int n_in,
                              void* d_out, int out_size, void* d_ws, size_t ws_size,
                              hipStream_t stream)
{
    const float* user_feats = (const float*)d_in[1];
    const int*   gnf        = (const int*)d_in[2];
    const int*   gei        = (const int*)d_in[3];
    const int*   tnf        = (const int*)d_in[4];
    const int*   tei        = (const int*)d_in[5];
    const int*   indices    = (const int*)d_in[6];
    const float* h0g        = (const float*)d_in[7];
    const float* h0t        = (const float*)d_in[8];
    const float* temb       = (const float*)d_in[9];
    const float* gW[2][4] = {{(const float*)d_in[10], (const float*)d_in[11], (const float*)d_in[12], (const float*)d_in[13]},
                             {(const float*)d_in[14], (const float*)d_in[15], (const float*)d_in[16], (const float*)d_in[17]}};
    const float* tW[2][4] = {{(const float*)d_in[18], (const float*)d_in[19], (const float*)d_in[20], (const float*)d_in[21]},
                             {(const float*)d_in[22], (const float*)d_in[23], (const float*)d_in[24], (const float*)d_in[25]}};
    const float* uW1 = (const float*)d_in[26]; const float* ub1 = (const float*)d_in[27];
    const float* uW2 = (const float*)d_in[28]; const float* ub2 = (const float*)d_in[29];
    const float* gc1W = (const float*)d_in[30]; const float* gc1as = (const float*)d_in[31];
    const float* gc1ad = (const float*)d_in[32]; const float* gc1b = (const float*)d_in[33];
    const float* gc2W = (const float*)d_in[34]; const float* gc2as = (const float*)d_in[35];
    const float* gc2ad = (const float*)d_in[36]; const float* gc2b = (const float*)d_in[37];
    const float* tc1W = (const float*)d_in[38]; const float* tc1as = (const float*)d_in[39];
    const float* tc1ad = (const float*)d_in[40]; const float* tc1b = (const float*)d_in[41];
    const float* tc2W = (const float*)d_in[42]; const float* tc2as = (const float*)d_in[43];
    const float* tc2ad = (const float*)d_in[44]; const float* tc2b = (const float*)d_in[45];
    const float* fcW = (const float*)d_in[46]; const float* fcb = (const float*)d_in[47];
    float* out = (float*)d_out;

    char* ws = (char*)d_ws;
    const size_t NEED = 226500000;
    if (ws_size < NEED) return;

    // ---- workspace layout (decimal byte offsets) ----
    float* XGF    = (float*)(ws + 0);            // 12 MB xg_final fp32 [NG][100]
    u16*   TEMB_B = (u16*)(ws + 12000000);       // 12.8 MB [VOC][128]
    u16*   ETAB_G = (u16*)(ws + 25000000);       // 30.4 MB [VOC][304]
    u16*   ETAB_T = (u16*)(ws + 60400000);       // 30.4 MB
    u16*   GH1B   = (u16*)(ws + 96000000);       // 2.56 MB [NTG][128]
    u16*   TH1B   = (u16*)(ws + 98600000);       // 7.68 MB [NTREE][128]
    float* UE     = (float*)(ws + 106400000);    // 8 MB
    float* HID    = (float*)(ws + 114400000);    // 8 MB
    u16*   WARENA = (u16*)(ws + 122400000);      // ~0.94 MB
    int*   GOFF   = (int*)(ws + 123600000);
    int*   GCUR   = (int*)(ws + 123800000);
    int*   GCNT   = (int*)(ws + 124000000);
    int*   GEIDX  = (int*)(ws + 124200000);      // 0.92 MB
    int*   TOFF   = (int*)(ws + 125200000);
    int*   TCUR   = (int*)(ws + 125400000);
    int*   TCNT   = (int*)(ws + 125600000);
    int*   TEIDX  = (int*)(ws + 125800000);      // 0.36 MB
    float* ESB    = (float*)(ws + 126200000);
    float* EDB    = (float*)(ws + 127200000);
    float* MB     = (float*)(ws + 128200000);
    float* SB     = (float*)(ws + 129200000);
    float* EBB    = (float*)(ws + 130200000);    // 7.36 MB
    float* SSUM   = (float*)(ws + 137600000);
    float* SCNT   = (float*)(ws + 137700000);
    u16*   XG_B   = (u16*)(ws + 138000000);      // 7.68 MB [NG][128]
    u16*   GFEAT1 = (u16*)(ws + 146000000);      // 30.72 MB [NG][512]
    u16*   GOUT1B = (u16*)(ws + 177000000);      // 30.72 MB
    u16*   GFEAT2 = (u16*)(ws + 208000000);      // 6 MB [NG][100]
    u16*   TFEAT1 = (u16*)(ws + 25000000);       // 48 MB [NTREE][800] (overlays Etabs, dead)
    u16*   TOUT1B = (u16*)(ws + 146000000);      // 48 MB (overlays GFEAT1/GOUT1B, dead)
    u16*   TFEAT2 = (u16*)(ws + 208000000);      // 6 MB (overlay GFEAT2, dead)
    float* XOUT2  = (float*)(ws + 214400000);    // 12 MB -> 226.4 MB

    // weight arena slots (u16 element offsets); each GRU W = [320][128]
    u16* gWHH0 = WARENA + 0;
    u16* gWIH1 = WARENA + 40960;
    u16* gWHH1 = WARENA + 81920;
    u16* tWHH0 = WARENA + 122880;
    u16* tWIH1 = WARENA + 163840;
    u16* tWHH1 = WARENA + 204800;
    u16* W_IH0 = WARENA + 245760;    // [320][128] scratch for Etab builds
    u16* W_G1  = WARENA + 286720;    // up to [800][128]
    u16* W_G2  = WARENA + 389120;    // up to [100][800]

    auto cvt = [&](const float* src, u16* dst, int M, int Mp, int K, int ldk,
                   const float* app = nullptr, int appone = 0) {
        convert_pad2<<<((size_t)Mp * ldk + 255) / 256, 256, 0, stream>>>(
            src, dst, M, Mp, K, ldk, app, appone);
    };
    auto mfma = [&](const u16* A, int lda, const u16* W, int ldw,
                    float* Cf, u16* Cb, int ldc, int M, int N, int Kt) {
        dim3 grid((M + 63) / 64, (N + 63) / 64, 1);
        gemm_mfma<<<grid, 256, 0, stream>>>(A, W, Cf, Cb, M, N, Kt, lda, ldw, ldc);
    };
    auto csr_build = [&](const int* ei, int E, int N, int* cnt, int* off, int* cur, int* eidx) {
        hipMemsetAsync(cnt, 0, (size_t)N * 4, stream);
        csr_count<<<(E + N + 255) / 256, 256, 0, stream>>>(ei, E, N, cnt);
        csr_scan<<<1, 256, 0, stream>>>(cnt, off, cur, N);
        csr_scatter<<<(E + N + 255) / 256, 256, 0, stream>>>(ei, E, N, cur, eidx);
    };
    auto gat_pre = [&](const u16* feat, int N, int heads, int C,
                       const float* asrc, const float* adst, const int* ei, int E) {
        gat_es_ed<<<(N * heads + 255) / 256, 256, 0, stream>>>(feat, asrc, adst, ESB, EDB, N, heads, C);
        hipMemsetAsync(MB, 0xFF, (size_t)N * heads * 4, stream);
        hipMemsetAsync(SB, 0, (size_t)N * heads * 4, stream);
        int EE = E + N;
        gat_edge_logit<<<(EE * heads + 255) / 256, 256, 0, stream>>>(ei, E, N, heads, ESB, EDB, EBB, MB);
        gat_edge_expsum<<<(EE * heads + 255) / 256, 256, 0, stream>>>(ei, E, N, heads, EBB, MB, SB);
    };

    // ---- 1. user embed (fp32) ----
    {
        dim3 g1((NU + 63) / 64, (HD + 63) / 64, 1);
        gemm_nt<<<g1, 256, 0, stream>>>(user_feats, uW1, ub1, HID, NU, HD, 9, 1);
        gemm_nt<<<g1, 256, 0, stream>>>(HID, uW2, ub2, UE, NU, HD, HD, 0);
    }

    // ---- 2. converts (+bias fold into col 100) + Etab builds ----
    cvt(temb, TEMB_B, VOC, VOC, HD, 128, nullptr, 1);           // col100 = 1
    cvt(gW[0][1], gWHH0, 300, 320, HD, 128, gW[0][3]);          // + bhh0
    cvt(gW[1][0], gWIH1, 300, 320, HD, 128, gW[1][2]);          // + bih1
    cvt(gW[1][1], gWHH1, 300, 320, HD, 128, gW[1][3]);          // + bhh1
    cvt(tW[0][1], tWHH0, 300, 320, HD, 128, tW[0][3]);
    cvt(tW[1][0], tWIH1, 300, 320, HD, 128, tW[1][2]);
    cvt(tW[1][1], tWHH1, 300, 320, HD, 128, tW[1][3]);
    cvt(gW[0][0], W_IH0, 300, 320, HD, 128, gW[0][2]);          // + bih0
    mfma(TEMB_B, 128, W_IH0, 128, nullptr, ETAB_G, ESTR, VOC, 300, 4);
    cvt(tW[0][0], W_IH0, 300, 320, HD, 128, tW[0][2]);
    mfma(TEMB_B, 128, W_IH0, 128, nullptr, ETAB_T, ESTR, VOC, 300, 4);

    // CSR for both graphs
    csr_build(gei, EG, NG, GCNT, GOFF, GCUR, GEIDX);
    csr_build(tei, ET, NTREE, TCNT, TOFF, TCUR, TEIDX);

    // ---- 3. combined GRU (both branches, one launch) ----
    {
        GruProb Pg = { ETAB_G, gnf, h0g, gWHH0, gWIH1, gWHH1, GH1B, NTG };
        GruProb Pt = { ETAB_T, tnf, h0t, tWHH0, tWIH1, tWHH1, TH1B, NTREE };
        int gblk = (NTG + 31) / 32;      // 313
        int tblk = (NTREE + 31) / 32;    // 938
        gru_fused4<<<gblk + tblk, 256, 0, stream>>>(Pg, Pt, gblk);
    }

    // ---- 4. graph GAT chain ----
    build_xg_bf<<<(NG * 128 + 255) / 256, 256, 0, stream>>>(GH1B, UE, XG_B);
    cvt(gc1W, W_G1, 512, 512, HD, 128);
    cvt(gc2W, W_G2, 100, 100, 512, 512);
    {   // graph GAT1: 8 heads x 64
        mfma(XG_B, 128, W_G1, 128, nullptr, GFEAT1, 512, NG, 512, 4);
        gat_pre(GFEAT1, NG, 8, 64, gc1as, gc1ad, gei, EG);
        int waves = NG * 2;
        gat_accum_csr<64, 4><<<(waves + 3) / 4, 256, 0, stream>>>(
            GOFF, GEIDX, gei, EG, EBB, SB, GFEAT1, gc1b, nullptr, GOUT1B, NG, 8, 512, 2);
    }
    {   // graph GAT2: 1 head x 100
        mfma(GOUT1B, 512, W_G2, 512, nullptr, GFEAT2, 100, NG, 100, 16);
        gat_pre(GFEAT2, NG, 1, 100, gc2as, gc2ad, gei, EG);
        int waves = NG;
        gat_accum_csr<100, 2><<<(waves + 3) / 4, 256, 0, stream>>>(
            GOFF, GEIDX, gei, EG, EBB, SB, GFEAT2, gc2b, XGF, nullptr, NG, 1, 100, 1);
    }

    // ---- 5. tree GAT chain ----
    set_roots<<<(NB * HD + 255) / 256, 256, 0, stream>>>(XGF, TH1B);
    cvt(tc1W, W_G1, 800, 800, HD, 128);
    cvt(tc2W, W_G2, 100, 100, 800, 800);
    {   // tree GAT1: 8 heads x 100
        mfma(TH1B, 128, W_G1, 128, nullptr, TFEAT1, 800, NTREE, 800, 4);
        gat_pre(TFEAT1, NTREE, 8, 100, tc1as, tc1ad, tei, ET);
        int waves = NTREE * 4;
        gat_accum_csr<100, 4><<<(waves + 3) / 4, 256, 0, stream>>>(
            TOFF, TEIDX, tei, ET, EBB, SB, TFEAT1, tc1b, nullptr, TOUT1B, NTREE, 8, 800, 4);
    }
    {   // tree GAT2: 1 head x 100
        mfma(TOUT1B, 800, W_G2, 800, nullptr, TFEAT2, 100, NTREE, 100, 25);
        gat_pre(TFEAT2, NTREE, 1, 100, tc2as, tc2ad, tei, ET);
        int waves = NTREE;
        gat_accum_csr<100, 2><<<(waves + 3) / 4, 256, 0, stream>>>(
            TOFF, TEIDX, tei, ET, EBB, SB, TFEAT2, tc2b, XOUT2, nullptr, NTREE, 1, 100, 1);
    }

    // ---- 6. scatter_mean + classifier ----
    hipMemsetAsync(SSUM, 0, (size_t)NB * HD * 4, stream);
    hipMemsetAsync(SCNT, 0, (size_t)NB * 4, stream);
    scatter_mean_accum<<<(NTREE * HD + 255) / 256, 256, 0, stream>>>(XOUT2, indices, SSUM, SCNT);
    fc_out<<<1, 512, 0, stream>>>(SSUM, SCNT, fcW, fcb, out);
}

// Round 8
// 1980.390 us; speedup vs baseline: 1.7374x; 1.4625x over previous
//
#include <hip/hip_runtime.h>

// ---------------------------------------------------------------------------
// Problem constants
// ---------------------------------------------------------------------------
#define NB    128
#define HD    100
#define NU    20000
#define NTG   10000
#define NTREE 30000
#define NG    30000
#define TT    20
#define EG    200000
#define ET    60000
#define VOC   50000

#define ESTR  304   // Etab row stride (u16): 608 B, 16B-aligned
#define GASTR 416   // gate LDS row stride (u16): 0..299 gates, 300..399 hn

typedef unsigned short u16;
typedef unsigned int   u32;
typedef __attribute__((ext_vector_type(8))) short short8;
typedef __attribute__((ext_vector_type(4))) float floatx4;

__device__ __forceinline__ float sigmoidf_(float x) {
    return __fdividef(1.f, 1.f + __expf(-x));
}
__device__ __forceinline__ float tanhf_(float x) {
    return 1.f - __fdividef(2.f, __expf(2.f * x) + 1.f);
}
__device__ __forceinline__ u16 f2bf(float f) {
    u32 u = __float_as_uint(f);
    u32 r = (u + 0x7fffu + ((u >> 16) & 1u)) >> 16;
    return (u16)r;
}
__device__ __forceinline__ float bf2f(u16 h) {
    return __uint_as_float(((u32)h) << 16);
}

// ---------------------------------------------------------------------------
// Fused 2-layer GRU v5: 256 threads / 32 rows / all TT steps.
// - ALL weight MFMA B-fragments register-resident (loaded once, zero per-step
//   weight traffic) — per wave 5 col-tiles x 4 k-chunks x 3 matrices.
// - x-gate Etab gathers prefetched a FULL STEP ahead into registers (consumed
//   in combine0 of step t+1) — gather latency fully covered.
// - LDS only h mirrors + gate buffer (44 KB).
// - biases folded into the K=100 slot (h col100 == 1, W col100 == bias).
// ---------------------------------------------------------------------------
struct GruProb {
    const u16*   Etab;     // [VOC][304] (includes bih0)
    const int*   nodes;    // [M][TT]
    const float* h0;       // [2][M][100] fp32
    const u16*   Whh0;     // [320][128] (col100 = bhh0)
    const u16*   Wih1;     // (col100 = bih1)
    const u16*   Whh1;     // (col100 = bhh1)
    u16*         hout;     // [M][128]
    int          M;
};

__global__ __launch_bounds__(256) void gru_fused5(GruProb Pg, GruProb Pt, int gblocks)
{
    const bool isg = (int)blockIdx.x < gblocks;
    const GruProb P = isg ? Pg : Pt;
    const int bx = isg ? blockIdx.x : blockIdx.x - gblocks;
    const int M  = P.M;
    const int m0 = bx * 32;

    __shared__ u16 h0b[32 * 136];
    __shared__ u16 h1b[32 * 136];
    __shared__ u16 GA[32 * GASTR];

    const int tid  = threadIdx.x;
    const int wave = tid >> 6, lane = tid & 63;
    const int fr   = lane & 15, quad = lane >> 4;

    // combine mapping: 8 threads per row, 13-col runs (c0 max = 91)
    const int crow = tid >> 3;
    const int cgm  = m0 + crow;
    const int c0   = (tid & 7) * 13;
    const int L    = (100 - c0 < 13) ? (100 - c0) : 13;
    const bool cok = (cgm < M);

    // ---- register-resident weight fragments (col-tiles ct = wave + 4*s) ----
    short8 Bh0[5][4], Bx1[5][4], Bh1[5][4];
#pragma unroll
    for (int s = 0; s < 5; ++s) {
        const int ct = wave + 4 * s;            // 0..19; rows 304..319 are zero pad
        const size_t rb = (size_t)(ct * 16 + fr) * 128 + quad * 8;
#pragma unroll
        for (int kk = 0; kk < 4; ++kk) {
            Bh0[s][kk] = *(const short8*)(P.Whh0 + rb + kk * 32);
            Bx1[s][kk] = *(const short8*)(P.Wih1 + rb + kk * 32);
            Bh1[s][kk] = *(const short8*)(P.Whh1 + rb + kk * 32);
        }
    }

    // ---- init h LDS mirrors + register carry ----
    for (int i = tid; i < 32 * 136; i += 256) { h0b[i] = 0; h1b[i] = 0; }
    __syncthreads();
    if (tid < 32) {
        h0b[tid * 136 + 100] = 0x3F80;   // 1.0 bias slot
        h1b[tid * 136 + 100] = 0x3F80;
    }
    float h0f[13], h1f[13];
#pragma unroll
    for (int j = 0; j < 13; ++j) { h0f[j] = 0.f; h1f[j] = 0.f; }
    if (cok) {
#pragma unroll
        for (int j = 0; j < 13; ++j) if (j < L) {
            int c = c0 + j;
            float v0 = P.h0[(size_t)cgm * 100 + c];
            float v1 = P.h0[(size_t)(M + cgm) * 100 + c];
            h0f[j] = v0; h1f[j] = v1;
            h0b[crow * 136 + c] = f2bf(v0);
            h1b[crow * 136 + c] = f2bf(v1);
        }
    }

    // ---- prefetch x-gates for t=0 (scalar u16, independent loads) ----
    u16 xr[13], xz[13], xn[13];
    {
        int nd = cok ? P.nodes[(size_t)cgm * TT] : 0;
        const u16* ex = P.Etab + (size_t)nd * ESTR + c0;
#pragma unroll
        for (int j = 0; j < 13; ++j) {
            xr[j] = ex[j];
            xz[j] = ex[100 + j];
            xn[j] = ex[200 + j];
        }
    }
    __syncthreads();

    for (int t = 0; t < TT; ++t) {
        // issue next node-id load early (consumed by the mid-step prefetch)
        int nd_next = (t + 1 < TT && cok) ? P.nodes[(size_t)cgm * TT + t + 1] : 0;

        // ---- GEMM0: Gh0 = h0 @ Whh0^T -> GA cols 0..299 ----
#pragma unroll
        for (int rt = 0; rt < 2; ++rt) {
            short8 a[4];
#pragma unroll
            for (int kk = 0; kk < 4; ++kk)
                a[kk] = *(const short8*)&h0b[(rt * 16 + fr) * 136 + kk * 32 + quad * 8];
#pragma unroll
            for (int s = 0; s < 5; ++s) {
                floatx4 acc = {0.f, 0.f, 0.f, 0.f};
#pragma unroll
                for (int kk = 0; kk < 4; ++kk)
                    acc = __builtin_amdgcn_mfma_f32_16x16x32_bf16(a[kk], Bh0[s][kk], acc, 0, 0, 0);
                int col = (wave + 4 * s) * 16 + fr;
                if (col < 300) {
                    int rbase = rt * 16 + quad * 4;
#pragma unroll
                    for (int r = 0; r < 4; ++r)
                        GA[(rbase + r) * GASTR + col] = f2bf(acc[r]);
                }
            }
        }
        __syncthreads();

        // ---- combine layer 0 (consume prefetched x-gates) ----
        if (cok) {
#pragma unroll
            for (int j = 0; j < 13; ++j) if (j < L) {
                int c = c0 + j;
                float hrg = bf2f(GA[crow * GASTR + c]);
                float hzg = bf2f(GA[crow * GASTR + 100 + c]);
                float hng = bf2f(GA[crow * GASTR + 200 + c]);
                float r  = sigmoidf_(bf2f(xr[j]) + hrg);
                float zz = sigmoidf_(bf2f(xz[j]) + hzg);
                float ng = tanhf_(bf2f(xn[j]) + r * hng);
                float o  = (1.f - zz) * ng + zz * h0f[j];
                h0f[j] = o;
                h0b[crow * 136 + c] = f2bf(o);
            }
        }
        // ---- prefetch x-gates for t+1 (covered by GEMM1..GEMM0-next) ----
        {
            const u16* ex = P.Etab + (size_t)nd_next * ESTR + c0;
#pragma unroll
            for (int j = 0; j < 13; ++j) {
                xr[j] = ex[j];
                xz[j] = ex[100 + j];
                xn[j] = ex[200 + j];
            }
        }
        __syncthreads();

        // ---- GEMM1: Gx1 = h0@Wih1^T, Gh1 = h1@Whh1^T ----
#pragma unroll
        for (int rt = 0; rt < 2; ++rt) {
            short8 a0[4], a1[4];
#pragma unroll
            for (int kk = 0; kk < 4; ++kk) {
                a0[kk] = *(const short8*)&h0b[(rt * 16 + fr) * 136 + kk * 32 + quad * 8];
                a1[kk] = *(const short8*)&h1b[(rt * 16 + fr) * 136 + kk * 32 + quad * 8];
            }
#pragma unroll
            for (int s = 0; s < 5; ++s) {
                floatx4 ax = {0.f, 0.f, 0.f, 0.f};
                floatx4 ah = {0.f, 0.f, 0.f, 0.f};
#pragma unroll
                for (int kk = 0; kk < 4; ++kk) {
                    ax = __builtin_amdgcn_mfma_f32_16x16x32_bf16(a0[kk], Bx1[s][kk], ax, 0, 0, 0);
                    ah = __builtin_amdgcn_mfma_f32_16x16x32_bf16(a1[kk], Bh1[s][kk], ah, 0, 0, 0);
                }
                int col = (wave + 4 * s) * 16 + fr;
                if (col < 300) {
                    int rbase = rt * 16 + quad * 4;
                    if (col < 200) {
#pragma unroll
                        for (int r = 0; r < 4; ++r)
                            GA[(rbase + r) * GASTR + col] = f2bf(ax[r] + ah[r]);
                    } else {
#pragma unroll
                        for (int r = 0; r < 4; ++r) {
                            GA[(rbase + r) * GASTR + col] = f2bf(ax[r]);
                            GA[(rbase + r) * GASTR + 100 + col] = f2bf(ah[r]);
                        }
                    }
                }
            }
        }
        __syncthreads();

        // ---- combine layer 1 ----
        if (cok) {
#pragma unroll
            for (int j = 0; j < 13; ++j) if (j < L) {
                int c = c0 + j;
                float sr_ = bf2f(GA[crow * GASTR + c]);
                float sz_ = bf2f(GA[crow * GASTR + 100 + c]);
                float xn_ = bf2f(GA[crow * GASTR + 200 + c]);
                float hn_ = bf2f(GA[crow * GASTR + 300 + c]);
                float r  = sigmoidf_(sr_);
                float zz = sigmoidf_(sz_);
                float ng = tanhf_(xn_ + r * hn_);
                float o  = (1.f - zz) * ng + zz * h1f[j];
                h1f[j] = o;
                h1b[crow * 136 + c] = f2bf(o);
            }
        }
        __syncthreads();   // protects GA (WAR vs next GEMM0) and h1b
    }

    // ---- write final top-layer hidden, bf16 [M][128] ----
    for (int i = tid; i < 32 * 128; i += 256) {
        int row = i >> 7, c = i & 127;
        int gm = m0 + row;
        if (gm < M)
            P.hout[(size_t)gm * 128 + c] = h1b[row * 136 + c];
    }
}

// ---------------------------------------------------------------------------
// bf16 MFMA GEMM (Etab build + GAT feature GEMMs)
// ---------------------------------------------------------------------------
#define LDST 40
__global__ __launch_bounds__(256) void gemm_mfma(
    const u16* __restrict__ A, const u16* __restrict__ B,
    float* __restrict__ Cf, u16* __restrict__ Cb,
    int M, int N, int Kt, int lda, int ldw, int ldc)
{
    const int m0 = blockIdx.x * 64;
    if (m0 >= M) return;
    const int n0 = blockIdx.y * 64;

    __shared__ u16 Als[64 * LDST];
    __shared__ u16 Wls[64 * LDST];

    const int tid  = threadIdx.x;
    const int wave = tid >> 6, lane = tid & 63;
    const int row  = tid >> 2, part = (tid & 3) * 8;
    const int fr   = lane & 15, quad = lane >> 4;

    floatx4 acc[4];
#pragma unroll
    for (int t = 0; t < 4; ++t) acc[t] = (floatx4){0.f, 0.f, 0.f, 0.f};

    const int am = m0 + row;  const bool aok = am < M;
    const int wn = n0 + row;  const bool wok = wn < N;
    const uint4 z4 = {0u, 0u, 0u, 0u};

    for (int kk = 0; kk < Kt; ++kk) {
        uint4 av = aok ? *(const uint4*)(A + (size_t)am * lda + kk * 32 + part) : z4;
        uint4 wv = wok ? *(const uint4*)(B + (size_t)wn * ldw + kk * 32 + part) : z4;
        __syncthreads();
        *(uint4*)&Als[row * LDST + part] = av;
        *(uint4*)&Wls[row * LDST + part] = wv;
        __syncthreads();
        short8 af = *(const short8*)&Als[((wave << 4) + fr) * LDST + quad * 8];
#pragma unroll
        for (int t = 0; t < 4; ++t) {
            short8 bf = *(const short8*)&Wls[((t << 4) + fr) * LDST + quad * 8];
            acc[t] = __builtin_amdgcn_mfma_f32_16x16x32_bf16(af, bf, acc[t], 0, 0, 0);
        }
    }

    const int orow0 = m0 + (wave << 4) + quad * 4;
#pragma unroll
    for (int t = 0; t < 4; ++t) {
        int col = n0 + (t << 4) + fr;
        if (col >= N) continue;
#pragma unroll
        for (int r = 0; r < 4; ++r) {
            int mr = orow0 + r;
            if (mr >= M) continue;
            float v = acc[t][r];
            if (Cf) Cf[(size_t)mr * ldc + col] = v;
            if (Cb) Cb[(size_t)mr * ldc + col] = f2bf(v);
        }
    }
}

// ---------------------------------------------------------------------------
// fp32 tiled GEMM (user-embed MLP only)
// ---------------------------------------------------------------------------
__global__ __launch_bounds__(256) void gemm_nt(
    const float* __restrict__ A, const float* __restrict__ W,
    const float* __restrict__ bias, float* __restrict__ C,
    int M, int N, int K, int relu)
{
    const int m0 = blockIdx.x * 64;
    const int n0 = blockIdx.y * 64;
    __shared__ float As[20][68];
    __shared__ float Ws[20][68];
    const int tid = threadIdx.x;
    const int r0 = (tid >> 4) * 4;
    const int c0 = (tid & 15) * 4;
    int sr[5], sk[5];
#pragma unroll
    for (int it = 0; it < 5; ++it) {
        int idx = tid + it * 256;
        sr[it] = idx / 20; sk[it] = idx - sr[it] * 20;
    }
    float acc[4][4];
#pragma unroll
    for (int i = 0; i < 4; ++i)
#pragma unroll
        for (int j = 0; j < 4; ++j) acc[i][j] = 0.f;
    const int nch = (K + 19) / 20;
    for (int ch = 0; ch < nch; ++ch) {
        const int k0 = ch * 20;
#pragma unroll
        for (int it = 0; it < 5; ++it) {
            int m = m0 + sr[it], k = k0 + sk[it];
            float va = 0.f, vw = 0.f;
            if (k < K) {
                if (m < M) va = A[(size_t)m * K + k];
                int n = n0 + sr[it];
                if (n < N) vw = W[(size_t)n * K + k];
            }
            As[sk[it]][sr[it]] = va;
            Ws[sk[it]][sr[it]] = vw;
        }
        __syncthreads();
#pragma unroll
        for (int kkk = 0; kkk < 20; ++kkk) {
            float4 a = *(const float4*)&As[kkk][r0];
            float4 w = *(const float4*)&Ws[kkk][c0];
            float av[4] = {a.x, a.y, a.z, a.w};
            float wv[4] = {w.x, w.y, w.z, w.w};
#pragma unroll
            for (int i = 0; i < 4; ++i)
#pragma unroll
                for (int j = 0; j < 4; ++j)
                    acc[i][j] = fmaf(av[i], wv[j], acc[i][j]);
        }
        __syncthreads();
    }
#pragma unroll
    for (int i = 0; i < 4; ++i) {
        int m = m0 + r0 + i;
        if (m >= M) continue;
#pragma unroll
        for (int j = 0; j < 4; ++j) {
            int n = n0 + c0 + j;
            if (n >= N) continue;
            float v = acc[i][j] + (bias ? bias[n] : 0.f);
            if (relu) v = fmaxf(v, 0.f);
            C[(size_t)m * N + n] = v;
        }
    }
}

// fp32 [M][K] -> bf16 [Mp][ldk]; col K..ldk zero, except col 100 gets
// app[n] (if app) or 1.0 (if appone) — the K-slot bias fold.
__global__ void convert_pad2(const float* __restrict__ src, u16* __restrict__ dst,
                             int M, int Mp, int K, int ldk,
                             const float* __restrict__ app, int appone)
{
    int t = blockIdx.x * blockDim.x + threadIdx.x;
    if (t >= Mp * ldk) return;
    int n = t / ldk, c = t - n * ldk;
    u16 o = 0;
    if (n < M) {
        if (c < K) o = f2bf(src[(size_t)n * K + c]);
        else if (c == 100) {
            if (app) o = f2bf(app[n]);
            else if (appone) o = 0x3F80;
        }
    }
    dst[t] = o;
}

// xg (bf16 [NG][128]) = concat(hg[:128], ue, hg[128:])
__global__ void build_xg_bf(const u16* __restrict__ hgb, const float* __restrict__ ue,
                            u16* __restrict__ xgb)
{
    int t = blockIdx.x * blockDim.x + threadIdx.x;
    if (t >= NG * 128) return;
    int n = t >> 7, c = t & 127;
    u16 o = 0;
    if (n < NB)           o = hgb[n * 128 + c];
    else if (n < NB + NU) { if (c < HD) o = f2bf(ue[(size_t)(n - NB) * HD + c]); }
    else                  o = hgb[(size_t)(n - NU) * 128 + c];
    xgb[t] = o;
}

// tree roots: hb rows[0:128) <- xg_final fp32
__global__ void set_roots(const float* __restrict__ src, u16* __restrict__ hb)
{
    int t = blockIdx.x * blockDim.x + threadIdx.x;
    if (t >= NB * HD) return;
    int n = t / HD, c = t - n * HD;
    hb[(size_t)n * 128 + c] = f2bf(src[t]);
}

// ---------------------------------------------------------------------------
// CSR build
// ---------------------------------------------------------------------------
__global__ void csr_count(const int* __restrict__ ei, int E, int N, int* __restrict__ cnt)
{
    int e = blockIdx.x * blockDim.x + threadIdx.x;
    if (e >= E + N) return;
    int dst = (e < E) ? ei[E + e] : e - E;
    atomicAdd(&cnt[dst], 1);
}

__global__ void csr_scan(const int* __restrict__ cnt, int* __restrict__ off,
                         int* __restrict__ cur, int N)
{
    __shared__ int part[256];
    const int tid = threadIdx.x;
    const int per = (N + 255) / 256;
    const int i0 = tid * per;
    const int i1 = min(i0 + per, N);
    int s = 0;
    for (int i = i0; i < i1; ++i) s += cnt[i];
    part[tid] = s;
    __syncthreads();
    for (int o = 1; o < 256; o <<= 1) {
        int u = (tid >= o) ? part[tid - o] : 0;
        __syncthreads();
        part[tid] += u;
        __syncthreads();
    }
    int base = part[tid] - s;
    for (int i = i0; i < i1; ++i) {
        off[i] = base; cur[i] = base;
        base += cnt[i];
    }
    if (tid == 255) off[N] = part[255];
}

__global__ void csr_scatter(const int* __restrict__ ei, int E, int N,
                            int* __restrict__ cur, int* __restrict__ eidx)
{
    int e = blockIdx.x * blockDim.x + threadIdx.x;
    if (e >= E + N) return;
    int dst = (e < E) ? ei[E + e] : e - E;
    int pos = atomicAdd(&cur[dst], 1);
    eidx[pos] = e;
}

// ---------------------------------------------------------------------------
// GAT pieces (feat is bf16)
// ---------------------------------------------------------------------------
__global__ void gat_es_ed(const u16* __restrict__ feat, const float* __restrict__ asrc,
                          const float* __restrict__ adst, float* __restrict__ es,
                          float* __restrict__ ed, int N, int heads, int C)
{
    int gid = blockIdx.x * blockDim.x + threadIdx.x;
    if (gid >= N * heads) return;
    int n = gid / heads, hd = gid - n * heads;
    const u16* hp = feat + ((size_t)n * heads + hd) * C;
    const float* as = asrc + (size_t)hd * C;
    const float* ad = adst + (size_t)hd * C;
    float s1 = 0.f, s2 = 0.f;
    for (int c = 0; c < C; c += 4) {
        uint2 pk = *(const uint2*)(hp + c);
        float v0 = bf2f((u16)(pk.x & 0xffff)), v1 = bf2f((u16)(pk.x >> 16));
        float v2 = bf2f((u16)(pk.y & 0xffff)), v3 = bf2f((u16)(pk.y >> 16));
        s1 += v0 * as[c] + v1 * as[c + 1] + v2 * as[c + 2] + v3 * as[c + 3];
        s2 += v0 * ad[c] + v1 * ad[c + 1] + v2 * ad[c + 2] + v3 * ad[c + 3];
    }
    es[gid] = s1; ed[gid] = s2;
}

__device__ __forceinline__ void atomic_max_f(float* addr, float v)
{
    if (v >= 0.f) atomicMax((int*)addr, __float_as_int(v));
    else          atomicMin((unsigned int*)addr, __float_as_uint(v));
}

__global__ void gat_edge_logit(const int* __restrict__ ei, int E, int N, int heads,
                               const float* __restrict__ es, const float* __restrict__ ed,
                               float* __restrict__ eb, float* __restrict__ m)
{
    int gid = blockIdx.x * blockDim.x + threadIdx.x;
    int EE = E + N;
    if (gid >= EE * heads) return;
    int idx = gid / heads, hd = gid - idx * heads;
    int src, dst;
    if (idx < E) { src = ei[idx]; dst = ei[E + idx]; } else { src = dst = idx - E; }
    float e = es[src * heads + hd] + ed[dst * heads + hd];
    e = e > 0.f ? e : 0.2f * e;
    eb[gid] = e;
    atomic_max_f(&m[dst * heads + hd], e);
}

__global__ void gat_edge_expsum(const int* __restrict__ ei, int E, int N, int heads,
                                float* __restrict__ eb, const float* __restrict__ m,
                                float* __restrict__ s)
{
    int gid = blockIdx.x * blockDim.x + threadIdx.x;
    int EE = E + N;
    if (gid >= EE * heads) return;
    int idx = gid / heads, hd = gid - idx * heads;
    int dst = (idx < E) ? ei[E + idx] : idx - E;
    float e = __expf(eb[gid] - m[dst * heads + hd]);
    eb[gid] = e;
    atomicAdd(&s[dst * heads + hd], e);
}

template<int C, int VEC>
__global__ __launch_bounds__(256) void gat_accum_csr(
    const int* __restrict__ off, const int* __restrict__ eidx,
    const int* __restrict__ ei, int E,
    const float* __restrict__ eb, const float* __restrict__ s,
    const u16* __restrict__ feat, const float* __restrict__ bias,
    float* __restrict__ outf, u16* __restrict__ outb,
    int N, int heads, int HC, int nchunk)
{
    int gt = blockIdx.x * blockDim.x + threadIdx.x;
    int w = gt >> 6, lane = gt & 63;
    int dst = w / nchunk, chunk = w - dst * nchunk;
    if (dst >= N) return;
    int c0 = chunk * 64 * VEC + lane * VEC;
    if (c0 >= HC) return;
    int hh[VEC]; float sinv[VEC], acc[VEC];
#pragma unroll
    for (int v = 0; v < VEC; ++v) {
        int c = c0 + v;
        hh[v] = c / C;
        sinv[v] = __fdividef(1.f, s[dst * heads + hh[v]]);
        acc[v] = 0.f;
    }
    int e0 = off[dst], e1 = off[dst + 1];
    for (int p = e0; p < e1; ++p) {
        int j = eidx[p];
        int src = (j < E) ? ei[j] : (j - E);
        const u16* frp = feat + (size_t)src * HC + c0;
        float fv[VEC];
        if (VEC == 4) {
            uint2 pk = *(const uint2*)frp;
            fv[0] = bf2f((u16)(pk.x & 0xffff)); fv[1] = bf2f((u16)(pk.x >> 16));
            fv[2] = bf2f((u16)(pk.y & 0xffff)); fv[3] = bf2f((u16)(pk.y >> 16));
        } else {
            u32 pk = *(const u32*)frp;
            fv[0] = bf2f((u16)(pk & 0xffff)); fv[1] = bf2f((u16)(pk >> 16));
        }
#pragma unroll
        for (int v = 0; v < VEC; ++v)
            acc[v] += fv[v] * eb[(size_t)j * heads + hh[v]] * sinv[v];
    }
#pragma unroll
    for (int v = 0; v < VEC; ++v) {
        int c = c0 + v;
        float o = fmaxf(acc[v] + bias[c], 0.f);
        if (outf) outf[(size_t)dst * HC + c] = o;
        if (outb) outb[(size_t)dst * HC + c] = f2bf(o);
    }
}

__global__ void scatter_mean_accum(const float* __restrict__ x, const int* __restrict__ idx,
                                   float* __restrict__ ssum, float* __restrict__ cnt)
{
    int t = blockIdx.x * blockDim.x + threadIdx.x;
    if (t >= NTREE * HD) return;
    int n = t / HD, c = t - n * HD;
    int b = idx[n];
    atomicAdd(&ssum[b * HD + c], x[t]);
    if (c == 0) atomicAdd(&cnt[b], 1.f);
}

__global__ void fc_out(const float* __restrict__ ssum, const float* __restrict__ cnt,
                       const float* __restrict__ W, const float* __restrict__ b,
                       float* __restrict__ out)
{
    int t = threadIdx.x;                 // 512 threads
    int bb = t >> 2, j = t & 3;
    float inv = __fdividef(1.f, fmaxf(cnt[bb], 1.f));
    float acc = b[j];
    for (int k = 0; k < HD; ++k) acc += ssum[bb * HD + k] * inv * W[j * HD + k];
    out[t] = acc;
}

// ---------------------------------------------------------------------------
// Host launcher
// ---------------------------------------------------------------------------
extern "C" void kernel_launch(void* const* d_in, const int* in_sizes, int n_in,
                              void* d_out, int out_size, void* d_ws, size_t ws_size,
                              hipStream_t stream)
{
    const float* user_feats = (const float*)d_in[1];
    const int*   gnf        = (const int*)d_in[2];
    const int*   gei        = (const int*)d_in[3];
    const int*   tnf        = (const int*)d_in[4];
    const int*   tei        = (const int*)d_in[5];
    const int*   indices    = (const int*)d_in[6];
    const float* h0g        = (const float*)d_in[7];
    const float* h0t        = (const float*)d_in[8];
    const float* temb       = (const float*)d_in[9];
    const float* gW[2][4] = {{(const float*)d_in[10], (const float*)d_in[11], (const float*)d_in[12], (const float*)d_in[13]},
                             {(const float*)d_in[14], (const float*)d_in[15], (const float*)d_in[16], (const float*)d_in[17]}};
    const float* tW[2][4] = {{(const float*)d_in[18], (const float*)d_in[19], (const float*)d_in[20], (const float*)d_in[21]},
                             {(const float*)d_in[22], (const float*)d_in[23], (const float*)d_in[24], (const float*)d_in[25]}};
    const float* uW1 = (const float*)d_in[26]; const float* ub1 = (const float*)d_in[27];
    const float* uW2 = (const float*)d_in[28]; const float* ub2 = (const float*)d_in[29];
    const float* gc1W = (const float*)d_in[30]; const float* gc1as = (const float*)d_in[31];
    const float* gc1ad = (const float*)d_in[32]; const float* gc1b = (const float*)d_in[33];
    const float* gc2W = (const float*)d_in[34]; const float* gc2as = (const float*)d_in[35];
    const float* gc2ad = (const float*)d_in[36]; const float* gc2b = (const float*)d_in[37];
    const float* tc1W = (const float*)d_in[38]; const float* tc1as = (const float*)d_in[39];
    const float* tc1ad = (const float*)d_in[40]; const float* tc1b = (const float*)d_in[41];
    const float* tc2W = (const float*)d_in[42]; const float* tc2as = (const float*)d_in[43];
    const float* tc2ad = (const float*)d_in[44]; const float* tc2b = (const float*)d_in[45];
    const float* fcW = (const float*)d_in[46]; const float* fcb = (const float*)d_in[47];
    float* out = (float*)d_out;

    char* ws = (char*)d_ws;
    const size_t NEED = 226500000;
    if (ws_size < NEED) return;

    // ---- workspace layout (decimal byte offsets) ----
    float* XGF    = (float*)(ws + 0);            // 12 MB xg_final fp32 [NG][100]
    u16*   TEMB_B = (u16*)(ws + 12000000);       // 12.8 MB [VOC][128]
    u16*   ETAB_G = (u16*)(ws + 25000000);       // 30.4 MB [VOC][304]
    u16*   ETAB_T = (u16*)(ws + 60400000);       // 30.4 MB
    u16*   GH1B   = (u16*)(ws + 96000000);       // 2.56 MB [NTG][128]
    u16*   TH1B   = (u16*)(ws + 98600000);       // 7.68 MB [NTREE][128]
    float* UE     = (float*)(ws + 106400000);    // 8 MB
    float* HID    = (float*)(ws + 114400000);    // 8 MB
    u16*   WARENA = (u16*)(ws + 122400000);      // ~0.94 MB
    int*   GOFF   = (int*)(ws + 123600000);
    int*   GCUR   = (int*)(ws + 123800000);
    int*   GCNT   = (int*)(ws + 124000000);
    int*   GEIDX  = (int*)(ws + 124200000);      // 0.92 MB
    int*   TOFF   = (int*)(ws + 125200000);
    int*   TCUR   = (int*)(ws + 125400000);
    int*   TCNT   = (int*)(ws + 125600000);
    int*   TEIDX  = (int*)(ws + 125800000);      // 0.36 MB
    float* ESB    = (float*)(ws + 126200000);
    float* EDB    = (float*)(ws + 127200000);
    float* MB     = (float*)(ws + 128200000);
    float* SB     = (float*)(ws + 129200000);
    float* EBB    = (float*)(ws + 130200000);    // 7.36 MB
    float* SSUM   = (float*)(ws + 137600000);
    float* SCNT   = (float*)(ws + 137700000);
    u16*   XG_B   = (u16*)(ws + 138000000);      // 7.68 MB [NG][128]
    u16*   GFEAT1 = (u16*)(ws + 146000000);      // 30.72 MB [NG][512]
    u16*   GOUT1B = (u16*)(ws + 177000000);      // 30.72 MB
    u16*   GFEAT2 = (u16*)(ws + 208000000);      // 6 MB [NG][100]
    u16*   TFEAT1 = (u16*)(ws + 25000000);       // 48 MB [NTREE][800] (overlays Etabs, dead)
    u16*   TOUT1B = (u16*)(ws + 146000000);      // 48 MB (overlays GFEAT1/GOUT1B, dead)
    u16*   TFEAT2 = (u16*)(ws + 208000000);      // 6 MB (overlay GFEAT2, dead)
    float* XOUT2  = (float*)(ws + 214400000);    // 12 MB -> 226.4 MB

    // weight arena slots (u16 element offsets); each GRU W = [320][128]
    u16* gWHH0 = WARENA + 0;
    u16* gWIH1 = WARENA + 40960;
    u16* gWHH1 = WARENA + 81920;
    u16* tWHH0 = WARENA + 122880;
    u16* tWIH1 = WARENA + 163840;
    u16* tWHH1 = WARENA + 204800;
    u16* W_IH0 = WARENA + 245760;    // [320][128] scratch for Etab builds
    u16* W_G1  = WARENA + 286720;    // up to [800][128]
    u16* W_G2  = WARENA + 389120;    // up to [100][800]

    auto cvt = [&](const float* src, u16* dst, int M, int Mp, int K, int ldk,
                   const float* app = nullptr, int appone = 0) {
        convert_pad2<<<((size_t)Mp * ldk + 255) / 256, 256, 0, stream>>>(
            src, dst, M, Mp, K, ldk, app, appone);
    };
    auto mfma = [&](const u16* A, int lda, const u16* W, int ldw,
                    float* Cf, u16* Cb, int ldc, int M, int N, int Kt) {
        dim3 grid((M + 63) / 64, (N + 63) / 64, 1);
        gemm_mfma<<<grid, 256, 0, stream>>>(A, W, Cf, Cb, M, N, Kt, lda, ldw, ldc);
    };
    auto csr_build = [&](const int* ei, int E, int N, int* cnt, int* off, int* cur, int* eidx) {
        hipMemsetAsync(cnt, 0, (size_t)N * 4, stream);
        csr_count<<<(E + N + 255) / 256, 256, 0, stream>>>(ei, E, N, cnt);
        csr_scan<<<1, 256, 0, stream>>>(cnt, off, cur, N);
        csr_scatter<<<(E + N + 255) / 256, 256, 0, stream>>>(ei, E, N, cur, eidx);
    };
    auto gat_pre = [&](const u16* feat, int N, int heads, int C,
                       const float* asrc, const float* adst, const int* ei, int E) {
        gat_es_ed<<<(N * heads + 255) / 256, 256, 0, stream>>>(feat, asrc, adst, ESB, EDB, N, heads, C);
        hipMemsetAsync(MB, 0xFF, (size_t)N * heads * 4, stream);
        hipMemsetAsync(SB, 0, (size_t)N * heads * 4, stream);
        int EE = E + N;
        gat_edge_logit<<<(EE * heads + 255) / 256, 256, 0, stream>>>(ei, E, N, heads, ESB, EDB, EBB, MB);
        gat_edge_expsum<<<(EE * heads + 255) / 256, 256, 0, stream>>>(ei, E, N, heads, EBB, MB, SB);
    };

    // ---- 1. user embed (fp32) ----
    {
        dim3 g1((NU + 63) / 64, (HD + 63) / 64, 1);
        gemm_nt<<<g1, 256, 0, stream>>>(user_feats, uW1, ub1, HID, NU, HD, 9, 1);
        gemm_nt<<<g1, 256, 0, stream>>>(HID, uW2, ub2, UE, NU, HD, HD, 0);
    }

    // ---- 2. converts (+bias fold into col 100) + Etab builds ----
    cvt(temb, TEMB_B, VOC, VOC, HD, 128, nullptr, 1);           // col100 = 1
    cvt(gW[0][1], gWHH0, 300, 320, HD, 128, gW[0][3]);          // + bhh0
    cvt(gW[1][0], gWIH1, 300, 320, HD, 128, gW[1][2]);          // + bih1
    cvt(gW[1][1], gWHH1, 300, 320, HD, 128, gW[1][3]);          // + bhh1
    cvt(tW[0][1], tWHH0, 300, 320, HD, 128, tW[0][3]);
    cvt(tW[1][0], tWIH1, 300, 320, HD, 128, tW[1][2]);
    cvt(tW[1][1], tWHH1, 300, 320, HD, 128, tW[1][3]);
    cvt(gW[0][0], W_IH0, 300, 320, HD, 128, gW[0][2]);          // + bih0
    mfma(TEMB_B, 128, W_IH0, 128, nullptr, ETAB_G, ESTR, VOC, 300, 4);
    cvt(tW[0][0], W_IH0, 300, 320, HD, 128, tW[0][2]);
    mfma(TEMB_B, 128, W_IH0, 128, nullptr, ETAB_T, ESTR, VOC, 300, 4);

    // CSR for both graphs
    csr_build(gei, EG, NG, GCNT, GOFF, GCUR, GEIDX);
    csr_build(tei, ET, NTREE, TCNT, TOFF, TCUR, TEIDX);

    // ---- 3. combined GRU (both branches, one launch) ----
    {
        GruProb Pg = { ETAB_G, gnf, h0g, gWHH0, gWIH1, gWHH1, GH1B, NTG };
        GruProb Pt = { ETAB_T, tnf, h0t, tWHH0, tWIH1, tWHH1, TH1B, NTREE };
        int gblk = (NTG + 31) / 32;      // 313
        int tblk = (NTREE + 31) / 32;    // 938
        gru_fused5<<<gblk + tblk, 256, 0, stream>>>(Pg, Pt, gblk);
    }

    // ---- 4. graph GAT chain ----
    build_xg_bf<<<(NG * 128 + 255) / 256, 256, 0, stream>>>(GH1B, UE, XG_B);
    cvt(gc1W, W_G1, 512, 512, HD, 128);
    cvt(gc2W, W_G2, 100, 100, 512, 512);
    {   // graph GAT1: 8 heads x 64
        mfma(XG_B, 128, W_G1, 128, nullptr, GFEAT1, 512, NG, 512, 4);
        gat_pre(GFEAT1, NG, 8, 64, gc1as, gc1ad, gei, EG);
        int waves = NG * 2;
        gat_accum_csr<64, 4><<<(waves + 3) / 4, 256, 0, stream>>>(
            GOFF, GEIDX, gei, EG, EBB, SB, GFEAT1, gc1b, nullptr, GOUT1B, NG, 8, 512, 2);
    }
    {   // graph GAT2: 1 head x 100
        mfma(GOUT1B, 512, W_G2, 512, nullptr, GFEAT2, 100, NG, 100, 16);
        gat_pre(GFEAT2, NG, 1, 100, gc2as, gc2ad, gei, EG);
        int waves = NG;
        gat_accum_csr<100, 2><<<(waves + 3) / 4, 256, 0, stream>>>(
            GOFF, GEIDX, gei, EG, EBB, SB, GFEAT2, gc2b, XGF, nullptr, NG, 1, 100, 1);
    }

    // ---- 5. tree GAT chain ----
    set_roots<<<(NB * HD + 255) / 256, 256, 0, stream>>>(XGF, TH1B);
    cvt(tc1W, W_G1, 800, 800, HD, 128);
    cvt(tc2W, W_G2, 100, 100, 800, 800);
    {   // tree GAT1: 8 heads x 100
        mfma(TH1B, 128, W_G1, 128, nullptr, TFEAT1, 800, NTREE, 800, 4);
        gat_pre(TFEAT1, NTREE, 8, 100, tc1as, tc1ad, tei, ET);
        int waves = NTREE * 4;
        gat_accum_csr<100, 4><<<(waves + 3) / 4, 256, 0, stream>>>(
            TOFF, TEIDX, tei, ET, EBB, SB, TFEAT1, tc1b, nullptr, TOUT1B, NTREE, 8, 800, 4);
    }
    {   // tree GAT2: 1 head x 100
        mfma(TOUT1B, 800, W_G2, 800, nullptr, TFEAT2, 100, NTREE, 100, 25);
        gat_pre(TFEAT2, NTREE, 1, 100, tc2as, tc2ad, tei, ET);
        int waves = NTREE;
        gat_accum_csr<100, 2><<<(waves + 3) / 4, 256, 0, stream>>>(
            TOFF, TEIDX, tei, ET, EBB, SB, TFEAT2, tc2b, XOUT2, nullptr, NTREE, 1, 100, 1);
    }

    // ---- 6. scatter_mean + classifier ----
    hipMemsetAsync(SSUM, 0, (size_t)NB * HD * 4, stream);
    hipMemsetAsync(SCNT, 0, (size_t)NB * 4, stream);
    scatter_mean_accum<<<(NTREE * HD + 255) / 256, 256, 0, stream>>>(XOUT2, indices, SSUM, SCNT);
    fc_out<<<1, 512, 0, stream>>>(SSUM, SCNT, fcW, fcb, out);
}